// Round 7
// baseline (1571.918 us; speedup 1.0000x reference)
//
#include <hip/hip_runtime.h>
#include <hip/hip_bf16.h>
#include <math.h>

#define NEGF (-1e30f)
#define LOG2E 1.44269504088896340736f
#define LN2 0.69314718055994530942f

// lp row layout for the CTC scan: 64 lane-groups x 8 floats (5 used, 3 pad)
#define LPROW 512

typedef short bf16x8 __attribute__((ext_vector_type(8)));
typedef float f32x4 __attribute__((ext_vector_type(4)));

__device__ __forceinline__ unsigned short f2b(float x) {
  __hip_bfloat16 h = __float2bfloat16(x);
  return *reinterpret_cast<unsigned short*>(&h);
}
__device__ __forceinline__ float b2f(unsigned short u) {
  __hip_bfloat16 h;
  *reinterpret_cast<unsigned short*>(&h) = u;
  return __bfloat162float(h);
}
__device__ __forceinline__ float gelu_exact(float x) {
  return 0.5f * x * (1.0f + erff(x * 0.70710678118654752440f));
}

#if __has_builtin(__builtin_amdgcn_exp2f)
__device__ __forceinline__ float fast_exp2(float x) { return __builtin_amdgcn_exp2f(x); }
#else
__device__ __forceinline__ float fast_exp2(float x) { return exp2f(x); }
#endif
#if __has_builtin(__builtin_amdgcn_logf)
__device__ __forceinline__ float fast_log2(float x) { return __builtin_amdgcn_logf(x); }
#else
__device__ __forceinline__ float fast_log2(float x) { return log2f(x); }
#endif

// ---------------------------------------------------------------------------
// W (K,N) fp32 -> WT (N,K) bf16, 32x32 LDS tile transpose
// ---------------------------------------------------------------------------
__global__ __launch_bounds__(256) void cvt_wt_kernel(
    const float* __restrict__ W, unsigned short* __restrict__ WT, int K, int N)
{
  __shared__ float tile[32][33];
  const int n0 = blockIdx.x * 32, k0 = blockIdx.y * 32;
  const int tx = threadIdx.x, ty = threadIdx.y;  // 32 x 8
#pragma unroll
  for (int i = 0; i < 32; i += 8) {
    int k = k0 + ty + i, n = n0 + tx;
    tile[ty + i][tx] = (k < K && n < N) ? W[(long)k * N + n] : 0.f;
  }
  __syncthreads();
#pragma unroll
  for (int i = 0; i < 32; i += 8) {
    int n = n0 + ty + i, k = k0 + tx;
    if (n < N && k < K) WT[(long)n * K + k] = f2b(tile[tx][ty + i]);
  }
}

// ---------------------------------------------------------------------------
// Unified bf16 MFMA GEMM, 32 rows x N cols per block, 8 waves.
// A staged in LDS in FRAGMENT ORDER (conflict-free ds_read_b128):
//   16B chunk (kc, mt, cl, g) at chunk index kc*128 + mt*64 + cl*4 + g,
//   holding A[row0 + mt*16 + cl][kc*32 + g*8 .. +8].
// B streamed per-lane from WT (N,K) with unroll-2 register double-buffer.
// EPI: 0 = bias only; 1 = bias + gelu + LayerNorm (full row in-block).
// AF32: A operand is fp32 (converted to bf16 during staging).
// ---------------------------------------------------------------------------
template<int K, int NT, int EPI, int AF32>
__global__ __launch_bounds__(512, 2) void gemm_bf16_kernel(
    const void* __restrict__ Ap, const unsigned short* __restrict__ WT,
    const float* __restrict__ bias, const float* __restrict__ lng,
    const float* __restrict__ lnb, unsigned short* __restrict__ out, long M)
{
  constexpr int N = NT * 8 * 16;
  constexpr int KC = K / 32;
  constexpr int NK2 = K / 64;
  extern __shared__ char smem[];
  unsigned short* as = (unsigned short*)smem;  // KC*128 chunks of 16B
  const int tid = threadIdx.x;
  const int lane = tid & 63;
  const int w = tid >> 6;
  const int cl = lane & 15, g = lane >> 4;
  const long row0 = (long)blockIdx.x * 32;
  const int n_base = w * (NT * 16);

  // ---- stage A (fragment order) ----
  constexpr int CH = KC * 128;
  for (int c = tid; c < CH; c += 512) {
    const int gg = c & 3, cc = (c >> 2) & 15, mt = (c >> 6) & 1, kc = c >> 7;
    const long row = row0 + mt * 16 + cc;
    const int k = kc * 32 + gg * 8;
    bf16x8 v;
    if (AF32) {
      const float* A = (const float*)Ap;
      const float4 f0 = *(const float4*)&A[row * K + k];
      const float4 f1 = *(const float4*)&A[row * K + k + 4];
      v[0] = (short)f2b(f0.x); v[1] = (short)f2b(f0.y);
      v[2] = (short)f2b(f0.z); v[3] = (short)f2b(f0.w);
      v[4] = (short)f2b(f1.x); v[5] = (short)f2b(f1.y);
      v[6] = (short)f2b(f1.z); v[7] = (short)f2b(f1.w);
    } else {
      const unsigned short* A = (const unsigned short*)Ap;
      v = *(const bf16x8*)&A[row * K + k];
    }
    *(bf16x8*)&as[c * 8] = v;
  }
  __syncthreads();

  f32x4 acc[2][NT];
#pragma unroll
  for (int mt = 0; mt < 2; ++mt)
#pragma unroll
    for (int nt = 0; nt < NT; ++nt) acc[mt][nt] = (f32x4){0.f, 0.f, 0.f, 0.f};

  const unsigned short* bptr = WT + (long)(n_base + cl) * K + g * 8;
  const int lofs = (cl * 4 + g) * 8;  // shorts

#define AFRAG(kc, mt) (*(const bf16x8*)&as[((kc) * 128 + (mt) * 64) * 8 + lofs])
#define MFMA_HALF(aa0, aa1, bb)                                                       \
  _Pragma("unroll")                                                                   \
  for (int nt = 0; nt < NT; ++nt) {                                                   \
    acc[0][nt] = __builtin_amdgcn_mfma_f32_16x16x32_bf16(aa0, bb[nt], acc[0][nt], 0, 0, 0); \
    acc[1][nt] = __builtin_amdgcn_mfma_f32_16x16x32_bf16(aa1, bb[nt], acc[1][nt], 0, 0, 0); \
  }

  bf16x8 b0[NT], b1[NT];
#pragma unroll
  for (int nt = 0; nt < NT; ++nt)
    b0[nt] = *(const bf16x8*)&bptr[(long)nt * 16 * K];

  for (int kc2 = 0; kc2 < NK2 - 1; ++kc2) {
    const int kk = kc2 * 64;
#pragma unroll
    for (int nt = 0; nt < NT; ++nt)
      b1[nt] = *(const bf16x8*)&bptr[(long)nt * 16 * K + kk + 32];
    {
      const bf16x8 a0 = AFRAG(2 * kc2, 0);
      const bf16x8 a1 = AFRAG(2 * kc2, 1);
      MFMA_HALF(a0, a1, b0)
    }
#pragma unroll
    for (int nt = 0; nt < NT; ++nt)
      b0[nt] = *(const bf16x8*)&bptr[(long)nt * 16 * K + kk + 64];
    {
      const bf16x8 a0 = AFRAG(2 * kc2 + 1, 0);
      const bf16x8 a1 = AFRAG(2 * kc2 + 1, 1);
      MFMA_HALF(a0, a1, b1)
    }
  }
  {  // tail k-block
    const int kk = (NK2 - 1) * 64;
#pragma unroll
    for (int nt = 0; nt < NT; ++nt)
      b1[nt] = *(const bf16x8*)&bptr[(long)nt * 16 * K + kk + 32];
    {
      const bf16x8 a0 = AFRAG(2 * (NK2 - 1), 0);
      const bf16x8 a1 = AFRAG(2 * (NK2 - 1), 1);
      MFMA_HALF(a0, a1, b0)
    }
    {
      const bf16x8 a0 = AFRAG(2 * (NK2 - 1) + 1, 0);
      const bf16x8 a1 = AFRAG(2 * (NK2 - 1) + 1, 1);
      MFMA_HALF(a0, a1, b1)
    }
  }
#undef AFRAG
#undef MFMA_HALF

  // ---- epilogue ----
  if (EPI == 0) {
    float bv[NT];
#pragma unroll
    for (int nt = 0; nt < NT; ++nt) bv[nt] = bias[n_base + nt * 16 + cl];
    __syncthreads();  // as dead; smem -> repack buffer [32][N] bf16
    unsigned short* rb = (unsigned short*)smem;
#pragma unroll
    for (int mt = 0; mt < 2; ++mt)
#pragma unroll
      for (int nt = 0; nt < NT; ++nt)
#pragma unroll
        for (int j = 0; j < 4; ++j)
          rb[(mt * 16 + g * 4 + j) * N + n_base + nt * 16 + cl] = f2b(acc[mt][nt][j] + bv[nt]);
    __syncthreads();
    constexpr int CH2 = 32 * (N / 8);
    for (int c = tid; c < CH2; c += 512) {
      int r = c / (N / 8);
      long row = row0 + r;
      if (row < M) {
        int nc = (c % (N / 8)) * 8;
        *(bf16x8*)&out[row * N + nc] = *(const bf16x8*)&rb[r * N + nc];
      }
    }
  } else {
    // bias + gelu (fp32), then LayerNorm over the full row (N == D)
#pragma unroll
    for (int nt = 0; nt < NT; ++nt) {
      float bvv = bias[n_base + nt * 16 + cl];
#pragma unroll
      for (int mt = 0; mt < 2; ++mt)
#pragma unroll
        for (int j = 0; j < 4; ++j)
          acc[mt][nt][j] = gelu_exact(acc[mt][nt][j] + bvv);
    }
    __syncthreads();  // as dead; smem -> reduction buffers
    float* redS = (float*)smem;          // [8][32]
    float* redQ = (float*)smem + 256;    // [8][32]
    float s1[2][4], s2[2][4];
#pragma unroll
    for (int mt = 0; mt < 2; ++mt)
#pragma unroll
      for (int j = 0; j < 4; ++j) {
        float a_ = 0.f, q_ = 0.f;
#pragma unroll
        for (int nt = 0; nt < NT; ++nt) {
          float x = acc[mt][nt][j];
          a_ += x; q_ += x * x;
        }
        s1[mt][j] = a_; s2[mt][j] = q_;
      }
#pragma unroll
    for (int off = 1; off < 16; off <<= 1)
#pragma unroll
      for (int mt = 0; mt < 2; ++mt)
#pragma unroll
        for (int j = 0; j < 4; ++j) {
          s1[mt][j] += __shfl_xor(s1[mt][j], off);
          s2[mt][j] += __shfl_xor(s2[mt][j], off);
        }
    if (cl == 0) {
#pragma unroll
      for (int mt = 0; mt < 2; ++mt)
#pragma unroll
        for (int j = 0; j < 4; ++j) {
          redS[w * 32 + mt * 16 + g * 4 + j] = s1[mt][j];
          redQ[w * 32 + mt * 16 + g * 4 + j] = s2[mt][j];
        }
    }
    __syncthreads();
    float mu[2][4], rs[2][4];
#pragma unroll
    for (int mt = 0; mt < 2; ++mt)
#pragma unroll
      for (int j = 0; j < 4; ++j) {
        float a_ = 0.f, q_ = 0.f;
#pragma unroll
        for (int ww = 0; ww < 8; ++ww) {
          a_ += redS[ww * 32 + mt * 16 + g * 4 + j];
          q_ += redQ[ww * 32 + mt * 16 + g * 4 + j];
        }
        float m_ = a_ * (1.f / N);
        float v_ = q_ * (1.f / N) - m_ * m_;
        mu[mt][j] = m_;
        rs[mt][j] = rsqrtf(v_ + 1e-6f);
      }
    __syncthreads();  // red buffers dead; smem -> repack
    unsigned short* rb = (unsigned short*)smem;
#pragma unroll
    for (int nt = 0; nt < NT; ++nt) {
      const int col = n_base + nt * 16 + cl;
      const float gv = lng[col], bv2 = lnb[col];
#pragma unroll
      for (int mt = 0; mt < 2; ++mt)
#pragma unroll
        for (int j = 0; j < 4; ++j) {
          float val = (acc[mt][nt][j] - mu[mt][j]) * rs[mt][j] * gv + bv2;
          rb[(mt * 16 + g * 4 + j) * N + col] = f2b(val);
        }
    }
    __syncthreads();
    constexpr int CH2 = 32 * (N / 8);
    for (int c = tid; c < CH2; c += 512) {
      int r = c / (N / 8);
      long row = row0 + r;
      if (row < M) {
        int nc = (c % (N / 8)) * 8;
        *(bf16x8*)&out[row * N + nc] = *(const bf16x8*)&rb[r * N + nc];
      }
    }
  }
}

// ---------------------------------------------------------------------------
// GEMM3 (V=1024) + bias + log_softmax + gather to lp_ext.
// Same fragment-ordered A + B double-buffer main loop.
// lp_ext layout: (B, T, LPROW): state s -> (s/5)*8 + s%5, log2 units.
// ---------------------------------------------------------------------------
template<int K>
__global__ __launch_bounds__(512, 2) void gemm3_bf16_kernel(
    const unsigned short* __restrict__ A, const unsigned short* __restrict__ WT,
    const float* __restrict__ bias, const int* __restrict__ targets,
    float* __restrict__ lp_ext, long M, int T, int B, int L, int S)
{
  constexpr int NT = 8, N = 1024;
  constexpr int KC = K / 32;
  constexpr int NK2 = K / 64;
  extern __shared__ char smem[];  // 65536
  unsigned short* as = (unsigned short*)smem;
  const int tid = threadIdx.x;
  const int lane = tid & 63;
  const int w = tid >> 6;
  const int cl = lane & 15, g = lane >> 4;
  const long row0 = (long)blockIdx.x * 32;
  const int n_base = w * (NT * 16);

  constexpr int CH = KC * 128;
  for (int c = tid; c < CH; c += 512) {
    const int gg = c & 3, cc = (c >> 2) & 15, mt = (c >> 6) & 1, kc = c >> 7;
    const long row = row0 + mt * 16 + cc;
    const int k = kc * 32 + gg * 8;
    *(bf16x8*)&as[c * 8] = *(const bf16x8*)&A[row * K + k];
  }
  __syncthreads();

  f32x4 acc[2][NT];
#pragma unroll
  for (int mt = 0; mt < 2; ++mt)
#pragma unroll
    for (int nt = 0; nt < NT; ++nt) acc[mt][nt] = (f32x4){0.f, 0.f, 0.f, 0.f};

  const unsigned short* bptr = WT + (long)(n_base + cl) * K + g * 8;
  const int lofs = (cl * 4 + g) * 8;

#define AFRAG(kc, mt) (*(const bf16x8*)&as[((kc) * 128 + (mt) * 64) * 8 + lofs])
#define MFMA_HALF(aa0, aa1, bb)                                                       \
  _Pragma("unroll")                                                                   \
  for (int nt = 0; nt < NT; ++nt) {                                                   \
    acc[0][nt] = __builtin_amdgcn_mfma_f32_16x16x32_bf16(aa0, bb[nt], acc[0][nt], 0, 0, 0); \
    acc[1][nt] = __builtin_amdgcn_mfma_f32_16x16x32_bf16(aa1, bb[nt], acc[1][nt], 0, 0, 0); \
  }

  bf16x8 b0[NT], b1[NT];
#pragma unroll
  for (int nt = 0; nt < NT; ++nt)
    b0[nt] = *(const bf16x8*)&bptr[(long)nt * 16 * K];

  for (int kc2 = 0; kc2 < NK2 - 1; ++kc2) {
    const int kk = kc2 * 64;
#pragma unroll
    for (int nt = 0; nt < NT; ++nt)
      b1[nt] = *(const bf16x8*)&bptr[(long)nt * 16 * K + kk + 32];
    {
      const bf16x8 a0 = AFRAG(2 * kc2, 0);
      const bf16x8 a1 = AFRAG(2 * kc2, 1);
      MFMA_HALF(a0, a1, b0)
    }
#pragma unroll
    for (int nt = 0; nt < NT; ++nt)
      b0[nt] = *(const bf16x8*)&bptr[(long)nt * 16 * K + kk + 64];
    {
      const bf16x8 a0 = AFRAG(2 * kc2 + 1, 0);
      const bf16x8 a1 = AFRAG(2 * kc2 + 1, 1);
      MFMA_HALF(a0, a1, b1)
    }
  }
  {
    const int kk = (NK2 - 1) * 64;
#pragma unroll
    for (int nt = 0; nt < NT; ++nt)
      b1[nt] = *(const bf16x8*)&bptr[(long)nt * 16 * K + kk + 32];
    {
      const bf16x8 a0 = AFRAG(2 * (NK2 - 1), 0);
      const bf16x8 a1 = AFRAG(2 * (NK2 - 1), 1);
      MFMA_HALF(a0, a1, b0)
    }
    {
      const bf16x8 a0 = AFRAG(2 * (NK2 - 1) + 1, 0);
      const bf16x8 a1 = AFRAG(2 * (NK2 - 1) + 1, 1);
      MFMA_HALF(a0, a1, b1)
    }
  }
#undef AFRAG
#undef MFMA_HALF

  // bias in fp32
#pragma unroll
  for (int nt = 0; nt < NT; ++nt) {
    float bvv = bias[n_base + nt * 16 + cl];
#pragma unroll
    for (int mt = 0; mt < 2; ++mt)
#pragma unroll
      for (int j = 0; j < 4; ++j) acc[mt][nt][j] += bvv;
  }

  __syncthreads();  // as dead
  float* redbuf = (float*)smem;  // [8][32]

  float rmax[2][4];
#pragma unroll
  for (int mt = 0; mt < 2; ++mt)
#pragma unroll
    for (int j = 0; j < 4; ++j) {
      float m = acc[mt][0][j];
#pragma unroll
      for (int nt = 1; nt < NT; ++nt) m = fmaxf(m, acc[mt][nt][j]);
      rmax[mt][j] = m;
    }
#pragma unroll
  for (int off = 1; off < 16; off <<= 1)
#pragma unroll
    for (int mt = 0; mt < 2; ++mt)
#pragma unroll
      for (int j = 0; j < 4; ++j)
        rmax[mt][j] = fmaxf(rmax[mt][j], __shfl_xor(rmax[mt][j], off));
  if (cl == 0) {
#pragma unroll
    for (int mt = 0; mt < 2; ++mt)
#pragma unroll
      for (int j = 0; j < 4; ++j) redbuf[w * 32 + mt * 16 + g * 4 + j] = rmax[mt][j];
  }
  __syncthreads();
  float rowmax[2][4];
#pragma unroll
  for (int mt = 0; mt < 2; ++mt)
#pragma unroll
    for (int j = 0; j < 4; ++j) {
      float m = redbuf[0 * 32 + mt * 16 + g * 4 + j];
#pragma unroll
      for (int ww = 1; ww < 8; ++ww) m = fmaxf(m, redbuf[ww * 32 + mt * 16 + g * 4 + j]);
      rowmax[mt][j] = m;
    }
  __syncthreads();

  float rsum[2][4];
#pragma unroll
  for (int mt = 0; mt < 2; ++mt)
#pragma unroll
    for (int j = 0; j < 4; ++j) {
      float s = 0.f;
#pragma unroll
      for (int nt = 0; nt < NT; ++nt) s += expf(acc[mt][nt][j] - rowmax[mt][j]);
      rsum[mt][j] = s;
    }
#pragma unroll
  for (int off = 1; off < 16; off <<= 1)
#pragma unroll
    for (int mt = 0; mt < 2; ++mt)
#pragma unroll
      for (int j = 0; j < 4; ++j) rsum[mt][j] += __shfl_xor(rsum[mt][j], off);
  if (cl == 0) {
#pragma unroll
    for (int mt = 0; mt < 2; ++mt)
#pragma unroll
      for (int j = 0; j < 4; ++j) redbuf[w * 32 + mt * 16 + g * 4 + j] = rsum[mt][j];
  }
  __syncthreads();
  float logz[2][4];
#pragma unroll
  for (int mt = 0; mt < 2; ++mt)
#pragma unroll
    for (int j = 0; j < 4; ++j) {
      float s = 0.f;
#pragma unroll
      for (int ww = 0; ww < 8; ++ww) s += redbuf[ww * 32 + mt * 16 + g * 4 + j];
      logz[mt][j] = rowmax[mt][j] + logf(s);
    }

  float* lpbuf = (float*)smem;  // [16][1024] = 64 KB
  for (int h = 0; h < 2; ++h) {
    __syncthreads();
#pragma unroll
    for (int nt = 0; nt < NT; ++nt)
#pragma unroll
      for (int j = 0; j < 4; ++j)
        lpbuf[(g * 4 + j) * 1024 + n_base + nt * 16 + cl] = acc[h][nt][j] - logz[h][j];
    __syncthreads();
    const int tot = 16 * S;
    for (int idx = tid; idx < tot; idx += 512) {
      int r = idx / S;
      int s = idx - r * S;
      long m = row0 + h * 16 + r;
      if (m < M) {
        int bb = (int)(m % B);
        int t = (int)(m / B);
        int lab = (s & 1) ? targets[bb * L + (s >> 1)] : 0;
        int grp = s / 5, rem = s - grp * 5;
        lp_ext[((long)bb * T + t) * LPROW + grp * 8 + rem] = lpbuf[r * 1024 + lab] * LOG2E;
      }
    }
  }
}

// ---------------------------------------------------------------------------
// CTC forward scan, base-2: one wave per batch element, alpha in registers
// (5 states/lane), neighbor exchange via shfl_up, CTC_DEPTH-deep register
// prefetch (aligned float4+float per lane via LPROW padding).
// ---------------------------------------------------------------------------
#define CTC_DEPTH 8
__global__ __launch_bounds__(64, 1) void ctc_scan_kernel(
    const float* __restrict__ lp2,  // (B, T, LPROW), log2 units
    const int* __restrict__ targets, const int* __restrict__ inlens,
    const int* __restrict__ tlens, float* __restrict__ partial,
    int T, int B, int L, int S)
{
  const int b = blockIdx.x;
  const int lane = threadIdx.x;
  const int s0 = lane * 5;
  const int inlen = inlens[b];
  const int tlen = tlens[b];
  const int send = 2 * tlen;
  const int capT = inlen - 1;

  bool valid[5], skipj[5];
#pragma unroll
  for (int j = 0; j < 5; ++j) {
    int s = s0 + j;
    valid[j] = (s < S);
    bool sk = false;
    if (valid[j] && (s & 1) && s >= 3) {
      int lab = targets[b * L + (s >> 1)];
      int lab2 = targets[b * L + (s >> 1) - 1];
      sk = (lab != 0) && (lab != lab2);
    }
    skipj[j] = sk;
  }

  const float* lpb = lp2 + (long)b * T * LPROW + lane * 8;

  float a[5];
  float lbv = NEGF, llv = NEGF;
#pragma unroll
  for (int j = 0; j < 5; ++j) {
    int s = s0 + j;
    a[j] = (valid[j] && s <= 1) ? lpb[j] : NEGF;
  }
  if (capT == 0) {
#pragma unroll
    for (int j = 0; j < 5; ++j) {
      int s = s0 + j;
      if (s == send) lbv = a[j];
      if (s == send - 1) llv = a[j];
    }
  }

  float4 b4[CTC_DEPTH];
  float b1[CTC_DEPTH];

#define CTC_ISSUE(d, t)                                \
  do {                                                 \
    const float* _p = lpb + (long)(t) * LPROW;         \
    b4[d] = *(const float4*)_p;                        \
    b1[d] = _p[4];                                     \
  } while (0)

#define CTC_PROCESS(tcur, d)                                                  \
  do {                                                                        \
    float lp_[5] = {b4[d].x, b4[d].y, b4[d].z, b4[d].w, b1[d]};               \
    float o_m1 = __shfl_up(a[4], 1);                                          \
    float o_m2 = __shfl_up(a[3], 1);                                          \
    if (lane == 0) { o_m1 = NEGF; o_m2 = NEGF; }                              \
    float na[5];                                                              \
    _Pragma("unroll")                                                         \
    for (int j = 0; j < 5; ++j) {                                             \
      float a0 = a[j];                                                        \
      float a1 = (j >= 1) ? a[j - 1] : o_m1;                                  \
      float a2 = skipj[j] ? ((j >= 2) ? a[j - 2] : o_m2) : NEGF;              \
      float m = fmaxf(fmaxf(a0, a1), a2);                                     \
      float sum = fast_exp2(a0 - m) + fast_exp2(a1 - m) + fast_exp2(a2 - m);  \
      float nv = m + fast_log2(sum) + lp_[j];                                 \
      na[j] = valid[j] ? nv : NEGF;                                           \
    }                                                                         \
    _Pragma("unroll")                                                         \
    for (int j = 0; j < 5; ++j) a[j] = na[j];                                 \
    if ((tcur) == capT) {                                                     \
      _Pragma("unroll")                                                       \
      for (int j = 0; j < 5; ++j) {                                           \
        int s = s0 + j;                                                       \
        if (s == send) lbv = a[j];                                            \
        if (s == send - 1) llv = a[j];                                        \
      }                                                                       \
    }                                                                         \
  } while (0)

#pragma unroll
  for (int d = 0; d < CTC_DEPTH; ++d) {
    int t = 1 + d;
    if (t < T) CTC_ISSUE(d, t);
  }

  int t = 1;
  for (; t <= T - 2 * CTC_DEPTH; t += CTC_DEPTH) {
#pragma unroll
    for (int d = 0; d < CTC_DEPTH; ++d) {
      CTC_PROCESS(t + d, d);
      CTC_ISSUE(d, t + d + CTC_DEPTH);
    }
  }
#pragma unroll
  for (int d = 0; d < CTC_DEPTH; ++d) {
    int tc = t + d;
    if (tc < T) {
      CTC_PROCESS(tc, d);
      int tn = tc + CTC_DEPTH;
      if (tn < T) CTC_ISSUE(d, tn);
    }
  }
  t += CTC_DEPTH;
#pragma unroll
  for (int d = 0; d < CTC_DEPTH; ++d) {
    int tc = t + d;
    if (tc < T) CTC_PROCESS(tc, d);
  }

#pragma unroll
  for (int off = 32; off; off >>= 1) {
    lbv = fmaxf(lbv, __shfl_xor(lbv, off));
    llv = fmaxf(llv, __shfl_xor(llv, off));
  }
  if (lane == 0) {
    float mx = fmaxf(lbv, llv);
    float l2 = mx + fast_log2(fast_exp2(lbv - mx) + fast_exp2(llv - mx));
    float loss = -LN2 * l2;
    if (!(loss <= 1e29f)) loss = 0.f;  // zero_infinity (also catches NaN)
    partial[b] = loss / (float)tlen;
  }
}

__global__ void reduce_kernel(const float* __restrict__ partial,
                              float* __restrict__ out, int B)
{
  int lane = threadIdx.x;
  float v = (lane < B) ? partial[lane] : 0.f;
#pragma unroll
  for (int off = 32; off; off >>= 1) v += __shfl_xor(v, off);
  if (lane == 0) out[0] = v / (float)B;
}

// ---------------------------------------------------------------------------
extern "C" void kernel_launch(void* const* d_in, const int* in_sizes, int n_in,
                              void* d_out, int out_size, void* d_ws, size_t ws_size,
                              hipStream_t stream) {
  const float* enc = (const float*)d_in[0];
  const float* Wp  = (const float*)d_in[1];
  const float* bp  = (const float*)d_in[2];
  const float* Wt  = (const float*)d_in[3];
  const float* btr = (const float*)d_in[4];
  const float* lng = (const float*)d_in[5];
  const float* lnb = (const float*)d_in[6];
  const float* Wd  = (const float*)d_in[7];
  const float* bd  = (const float*)d_in[8];
  const int* tgt   = (const int*)d_in[9];
  const int* inl   = (const int*)d_in[10];
  const int* tll   = (const int*)d_in[11];

  const int D = in_sizes[2];              // 768
  const int V = in_sizes[8];              // 1024
  const int B = in_sizes[10];             // 32
  const int L = in_sizes[9] / B;          // 150
  const long M = (long)in_sizes[0] / D;   // T*B = 64000
  const int T = (int)(M / B);             // 2000
  const int S = 2 * L + 1;                // 301

  char* wsb = (char*)d_ws;
  size_t off = 0;
  auto alloc = [&](size_t bytes) { char* p = wsb + off; off += (bytes + 255) & ~(size_t)255; return p; };
  unsigned short* X1b  = (unsigned short*)alloc((size_t)M * D * 2);
  unsigned short* X2b  = (unsigned short*)alloc((size_t)M * D * 2);
  float* LP            = (float*)alloc((size_t)B * T * LPROW * 4);
  unsigned short* WpT  = (unsigned short*)alloc((size_t)D * D * 2);
  unsigned short* WtT  = (unsigned short*)alloc((size_t)D * D * 2);
  unsigned short* WdT  = (unsigned short*)alloc((size_t)D * V * 2);
  float* partial       = (float*)alloc(256);

  cvt_wt_kernel<<<dim3(D / 32, D / 32), dim3(32, 8), 0, stream>>>(Wp, WpT, D, D);
  cvt_wt_kernel<<<dim3(D / 32, D / 32), dim3(32, 8), 0, stream>>>(Wt, WtT, D, D);
  cvt_wt_kernel<<<dim3(V / 32, D / 32), dim3(32, 8), 0, stream>>>(Wd, WdT, D, V);

  const int grid = (int)((M + 31) / 32);
  const size_t smem12 = 49152;  // max(A frag 48K, repack 48K)
  gemm_bf16_kernel<768, 6, 0, 1><<<grid, 512, smem12, stream>>>(
      (const void*)enc, WpT, bp, nullptr, nullptr, X1b, M);
  gemm_bf16_kernel<768, 6, 1, 0><<<grid, 512, smem12, stream>>>(
      (const void*)X1b, WtT, btr, lng, lnb, X2b, M);
  gemm3_bf16_kernel<768><<<grid, 512, 65536, stream>>>(
      X2b, WdT, bd, tgt, LP, M, T, B, L, S);

  ctc_scan_kernel<<<B, 64, 0, stream>>>(LP, tgt, inl, tll, partial, T, B, L, S);
  reduce_kernel<<<1, 64, 0, stream>>>(partial, (float*)d_out, B);
}

// Round 8
// 1566.809 us; speedup vs baseline: 1.0033x; 1.0033x over previous
//
#include <hip/hip_runtime.h>
#include <hip/hip_bf16.h>
#include <math.h>

#define NEGF (-1e30f)
#define LOG2E 1.44269504088896340736f
#define LN2 0.69314718055994530942f

// lp row layout for the CTC scan: 64 lane-groups x 8 floats (5 used, 3 pad)
#define LPROW 512

typedef short bf16x8 __attribute__((ext_vector_type(8)));
typedef float f32x4 __attribute__((ext_vector_type(4)));

__device__ __forceinline__ unsigned short f2b(float x) {
  __hip_bfloat16 h = __float2bfloat16(x);
  return *reinterpret_cast<unsigned short*>(&h);
}
__device__ __forceinline__ float b2f(unsigned short u) {
  __hip_bfloat16 h;
  *reinterpret_cast<unsigned short*>(&h) = u;
  return __bfloat162float(h);
}
__device__ __forceinline__ float gelu_exact(float x) {
  return 0.5f * x * (1.0f + erff(x * 0.70710678118654752440f));
}

#if __has_builtin(__builtin_amdgcn_exp2f)
__device__ __forceinline__ float fast_exp2(float x) { return __builtin_amdgcn_exp2f(x); }
#else
__device__ __forceinline__ float fast_exp2(float x) { return exp2f(x); }
#endif
#if __has_builtin(__builtin_amdgcn_logf)
__device__ __forceinline__ float fast_log2(float x) { return __builtin_amdgcn_logf(x); }
#else
__device__ __forceinline__ float fast_log2(float x) { return log2f(x); }
#endif

// ---------------------------------------------------------------------------
// W (K,N) fp32 -> WT (N,K) bf16, 32x32 LDS tile transpose
// ---------------------------------------------------------------------------
__global__ __launch_bounds__(256) void cvt_wt_kernel(
    const float* __restrict__ W, unsigned short* __restrict__ WT, int K, int N)
{
  __shared__ float tile[32][33];
  const int n0 = blockIdx.x * 32, k0 = blockIdx.y * 32;
  const int tx = threadIdx.x, ty = threadIdx.y;  // 32 x 8
#pragma unroll
  for (int i = 0; i < 32; i += 8) {
    int k = k0 + ty + i, n = n0 + tx;
    tile[ty + i][tx] = (k < K && n < N) ? W[(long)k * N + n] : 0.f;
  }
  __syncthreads();
#pragma unroll
  for (int i = 0; i < 32; i += 8) {
    int n = n0 + ty + i, k = k0 + tx;
    if (n < N && k < K) WT[(long)n * K + k] = f2b(tile[tx][ty + i]);
  }
}

// ---------------------------------------------------------------------------
// Unified bf16 MFMA GEMM, 32 rows x N cols per block, 8 waves.
// A staged in LDS in FRAGMENT ORDER (conflict-free ds_read_b128):
//   16B chunk (kc, mt, cl, g) at chunk index kc*128 + mt*64 + cl*4 + g,
//   holding A[row0 + mt*16 + cl][kc*32 + g*8 .. +8].
// B streamed per-lane from WT (N,K) with unroll-2 register double-buffer.
// EPI: 0 = bias only; 1 = bias + gelu + LayerNorm (full row in-block).
// AF32: A operand is fp32 (converted to bf16 during staging).
// ---------------------------------------------------------------------------
template<int K, int NT, int EPI, int AF32>
__global__ __launch_bounds__(512, 2) void gemm_bf16_kernel(
    const void* __restrict__ Ap, const unsigned short* __restrict__ WT,
    const float* __restrict__ bias, const float* __restrict__ lng,
    const float* __restrict__ lnb, unsigned short* __restrict__ out, long M)
{
  constexpr int N = NT * 8 * 16;
  constexpr int KC = K / 32;
  constexpr int NK2 = K / 64;
  extern __shared__ char smem[];
  unsigned short* as = (unsigned short*)smem;  // KC*128 chunks of 16B
  const int tid = threadIdx.x;
  const int lane = tid & 63;
  const int w = tid >> 6;
  const int cl = lane & 15, g = lane >> 4;
  const long row0 = (long)blockIdx.x * 32;
  const int n_base = w * (NT * 16);

  // ---- stage A (fragment order) ----
  constexpr int CH = KC * 128;
  for (int c = tid; c < CH; c += 512) {
    const int gg = c & 3, cc = (c >> 2) & 15, mt = (c >> 6) & 1, kc = c >> 7;
    const long row = row0 + mt * 16 + cc;
    const int k = kc * 32 + gg * 8;
    bf16x8 v;
    if (AF32) {
      const float* A = (const float*)Ap;
      const float4 f0 = *(const float4*)&A[row * K + k];
      const float4 f1 = *(const float4*)&A[row * K + k + 4];
      v[0] = (short)f2b(f0.x); v[1] = (short)f2b(f0.y);
      v[2] = (short)f2b(f0.z); v[3] = (short)f2b(f0.w);
      v[4] = (short)f2b(f1.x); v[5] = (short)f2b(f1.y);
      v[6] = (short)f2b(f1.z); v[7] = (short)f2b(f1.w);
    } else {
      const unsigned short* A = (const unsigned short*)Ap;
      v = *(const bf16x8*)&A[row * K + k];
    }
    *(bf16x8*)&as[c * 8] = v;
  }
  __syncthreads();

  f32x4 acc[2][NT];
#pragma unroll
  for (int mt = 0; mt < 2; ++mt)
#pragma unroll
    for (int nt = 0; nt < NT; ++nt) acc[mt][nt] = (f32x4){0.f, 0.f, 0.f, 0.f};

  const unsigned short* bptr = WT + (long)(n_base + cl) * K + g * 8;
  const int lofs = (cl * 4 + g) * 8;  // shorts

#define AFRAG(kc, mt) (*(const bf16x8*)&as[((kc) * 128 + (mt) * 64) * 8 + lofs])
#define MFMA_HALF(aa0, aa1, bb)                                                       \
  _Pragma("unroll")                                                                   \
  for (int nt = 0; nt < NT; ++nt) {                                                   \
    acc[0][nt] = __builtin_amdgcn_mfma_f32_16x16x32_bf16(aa0, bb[nt], acc[0][nt], 0, 0, 0); \
    acc[1][nt] = __builtin_amdgcn_mfma_f32_16x16x32_bf16(aa1, bb[nt], acc[1][nt], 0, 0, 0); \
  }

  bf16x8 b0[NT], b1[NT];
#pragma unroll
  for (int nt = 0; nt < NT; ++nt)
    b0[nt] = *(const bf16x8*)&bptr[(long)nt * 16 * K];

  for (int kc2 = 0; kc2 < NK2 - 1; ++kc2) {
    const int kk = kc2 * 64;
#pragma unroll
    for (int nt = 0; nt < NT; ++nt)
      b1[nt] = *(const bf16x8*)&bptr[(long)nt * 16 * K + kk + 32];
    {
      const bf16x8 a0 = AFRAG(2 * kc2, 0);
      const bf16x8 a1 = AFRAG(2 * kc2, 1);
      MFMA_HALF(a0, a1, b0)
    }
#pragma unroll
    for (int nt = 0; nt < NT; ++nt)
      b0[nt] = *(const bf16x8*)&bptr[(long)nt * 16 * K + kk + 64];
    {
      const bf16x8 a0 = AFRAG(2 * kc2 + 1, 0);
      const bf16x8 a1 = AFRAG(2 * kc2 + 1, 1);
      MFMA_HALF(a0, a1, b1)
    }
  }
  {  // tail k-block
    const int kk = (NK2 - 1) * 64;
#pragma unroll
    for (int nt = 0; nt < NT; ++nt)
      b1[nt] = *(const bf16x8*)&bptr[(long)nt * 16 * K + kk + 32];
    {
      const bf16x8 a0 = AFRAG(2 * (NK2 - 1), 0);
      const bf16x8 a1 = AFRAG(2 * (NK2 - 1), 1);
      MFMA_HALF(a0, a1, b0)
    }
    {
      const bf16x8 a0 = AFRAG(2 * (NK2 - 1) + 1, 0);
      const bf16x8 a1 = AFRAG(2 * (NK2 - 1) + 1, 1);
      MFMA_HALF(a0, a1, b1)
    }
  }
#undef AFRAG
#undef MFMA_HALF

  // ---- epilogue ----
  if (EPI == 0) {
    float bv[NT];
#pragma unroll
    for (int nt = 0; nt < NT; ++nt) bv[nt] = bias[n_base + nt * 16 + cl];
    __syncthreads();  // as dead; smem -> repack buffer [32][N] bf16
    unsigned short* rb = (unsigned short*)smem;
#pragma unroll
    for (int mt = 0; mt < 2; ++mt)
#pragma unroll
      for (int nt = 0; nt < NT; ++nt)
#pragma unroll
        for (int j = 0; j < 4; ++j)
          rb[(mt * 16 + g * 4 + j) * N + n_base + nt * 16 + cl] = f2b(acc[mt][nt][j] + bv[nt]);
    __syncthreads();
    constexpr int CH2 = 32 * (N / 8);
    for (int c = tid; c < CH2; c += 512) {
      int r = c / (N / 8);
      long row = row0 + r;
      if (row < M) {
        int nc = (c % (N / 8)) * 8;
        *(bf16x8*)&out[row * N + nc] = *(const bf16x8*)&rb[r * N + nc];
      }
    }
  } else {
    // bias + gelu (fp32), then LayerNorm over the full row (N == D)
#pragma unroll
    for (int nt = 0; nt < NT; ++nt) {
      float bvv = bias[n_base + nt * 16 + cl];
#pragma unroll
      for (int mt = 0; mt < 2; ++mt)
#pragma unroll
        for (int j = 0; j < 4; ++j)
          acc[mt][nt][j] = gelu_exact(acc[mt][nt][j] + bvv);
    }
    __syncthreads();  // as dead; smem -> reduction buffers
    float* redS = (float*)smem;          // [8][32]
    float* redQ = (float*)smem + 256;    // [8][32]
    float s1[2][4], s2[2][4];
#pragma unroll
    for (int mt = 0; mt < 2; ++mt)
#pragma unroll
      for (int j = 0; j < 4; ++j) {
        float a_ = 0.f, q_ = 0.f;
#pragma unroll
        for (int nt = 0; nt < NT; ++nt) {
          float x = acc[mt][nt][j];
          a_ += x; q_ += x * x;
        }
        s1[mt][j] = a_; s2[mt][j] = q_;
      }
#pragma unroll
    for (int off = 1; off < 16; off <<= 1)
#pragma unroll
      for (int mt = 0; mt < 2; ++mt)
#pragma unroll
        for (int j = 0; j < 4; ++j) {
          s1[mt][j] += __shfl_xor(s1[mt][j], off);
          s2[mt][j] += __shfl_xor(s2[mt][j], off);
        }
    if (cl == 0) {
#pragma unroll
      for (int mt = 0; mt < 2; ++mt)
#pragma unroll
        for (int j = 0; j < 4; ++j) {
          redS[w * 32 + mt * 16 + g * 4 + j] = s1[mt][j];
          redQ[w * 32 + mt * 16 + g * 4 + j] = s2[mt][j];
        }
    }
    __syncthreads();
    float mu[2][4], rs[2][4];
#pragma unroll
    for (int mt = 0; mt < 2; ++mt)
#pragma unroll
      for (int j = 0; j < 4; ++j) {
        float a_ = 0.f, q_ = 0.f;
#pragma unroll
        for (int ww = 0; ww < 8; ++ww) {
          a_ += redS[ww * 32 + mt * 16 + g * 4 + j];
          q_ += redQ[ww * 32 + mt * 16 + g * 4 + j];
        }
        float m_ = a_ * (1.f / N);
        float v_ = q_ * (1.f / N) - m_ * m_;
        mu[mt][j] = m_;
        rs[mt][j] = rsqrtf(v_ + 1e-6f);
      }
    __syncthreads();  // red buffers dead; smem -> repack
    unsigned short* rb = (unsigned short*)smem;
#pragma unroll
    for (int nt = 0; nt < NT; ++nt) {
      const int col = n_base + nt * 16 + cl;
      const float gv = lng[col], bv2 = lnb[col];
#pragma unroll
      for (int mt = 0; mt < 2; ++mt)
#pragma unroll
        for (int j = 0; j < 4; ++j) {
          float val = (acc[mt][nt][j] - mu[mt][j]) * rs[mt][j] * gv + bv2;
          rb[(mt * 16 + g * 4 + j) * N + col] = f2b(val);
        }
    }
    __syncthreads();
    constexpr int CH2 = 32 * (N / 8);
    for (int c = tid; c < CH2; c += 512) {
      int r = c / (N / 8);
      long row = row0 + r;
      if (row < M) {
        int nc = (c % (N / 8)) * 8;
        *(bf16x8*)&out[row * N + nc] = *(const bf16x8*)&rb[r * N + nc];
      }
    }
  }
}

// ---------------------------------------------------------------------------
// GEMM3 (V=1024) + bias + log_softmax + gather to lp_ext.
// Same fragment-ordered A + B double-buffer main loop.
// lp_ext layout: (B, T, LPROW): state s -> (s/5)*8 + s%5, log2 units.
// ---------------------------------------------------------------------------
template<int K>
__global__ __launch_bounds__(512, 2) void gemm3_bf16_kernel(
    const unsigned short* __restrict__ A, const unsigned short* __restrict__ WT,
    const float* __restrict__ bias, const int* __restrict__ targets,
    float* __restrict__ lp_ext, long M, int T, int B, int L, int S)
{
  constexpr int NT = 8, N = 1024;
  constexpr int KC = K / 32;
  constexpr int NK2 = K / 64;
  extern __shared__ char smem[];  // 65536
  unsigned short* as = (unsigned short*)smem;
  const int tid = threadIdx.x;
  const int lane = tid & 63;
  const int w = tid >> 6;
  const int cl = lane & 15, g = lane >> 4;
  const long row0 = (long)blockIdx.x * 32;
  const int n_base = w * (NT * 16);

  constexpr int CH = KC * 128;
  for (int c = tid; c < CH; c += 512) {
    const int gg = c & 3, cc = (c >> 2) & 15, mt = (c >> 6) & 1, kc = c >> 7;
    const long row = row0 + mt * 16 + cc;
    const int k = kc * 32 + gg * 8;
    *(bf16x8*)&as[c * 8] = *(const bf16x8*)&A[row * K + k];
  }
  __syncthreads();

  f32x4 acc[2][NT];
#pragma unroll
  for (int mt = 0; mt < 2; ++mt)
#pragma unroll
    for (int nt = 0; nt < NT; ++nt) acc[mt][nt] = (f32x4){0.f, 0.f, 0.f, 0.f};

  const unsigned short* bptr = WT + (long)(n_base + cl) * K + g * 8;
  const int lofs = (cl * 4 + g) * 8;

#define AFRAG(kc, mt) (*(const bf16x8*)&as[((kc) * 128 + (mt) * 64) * 8 + lofs])
#define MFMA_HALF(aa0, aa1, bb)                                                       \
  _Pragma("unroll")                                                                   \
  for (int nt = 0; nt < NT; ++nt) {                                                   \
    acc[0][nt] = __builtin_amdgcn_mfma_f32_16x16x32_bf16(aa0, bb[nt], acc[0][nt], 0, 0, 0); \
    acc[1][nt] = __builtin_amdgcn_mfma_f32_16x16x32_bf16(aa1, bb[nt], acc[1][nt], 0, 0, 0); \
  }

  bf16x8 b0[NT], b1[NT];
#pragma unroll
  for (int nt = 0; nt < NT; ++nt)
    b0[nt] = *(const bf16x8*)&bptr[(long)nt * 16 * K];

  for (int kc2 = 0; kc2 < NK2 - 1; ++kc2) {
    const int kk = kc2 * 64;
#pragma unroll
    for (int nt = 0; nt < NT; ++nt)
      b1[nt] = *(const bf16x8*)&bptr[(long)nt * 16 * K + kk + 32];
    {
      const bf16x8 a0 = AFRAG(2 * kc2, 0);
      const bf16x8 a1 = AFRAG(2 * kc2, 1);
      MFMA_HALF(a0, a1, b0)
    }
#pragma unroll
    for (int nt = 0; nt < NT; ++nt)
      b0[nt] = *(const bf16x8*)&bptr[(long)nt * 16 * K + kk + 64];
    {
      const bf16x8 a0 = AFRAG(2 * kc2 + 1, 0);
      const bf16x8 a1 = AFRAG(2 * kc2 + 1, 1);
      MFMA_HALF(a0, a1, b1)
    }
  }
  {
    const int kk = (NK2 - 1) * 64;
#pragma unroll
    for (int nt = 0; nt < NT; ++nt)
      b1[nt] = *(const bf16x8*)&bptr[(long)nt * 16 * K + kk + 32];
    {
      const bf16x8 a0 = AFRAG(2 * (NK2 - 1), 0);
      const bf16x8 a1 = AFRAG(2 * (NK2 - 1), 1);
      MFMA_HALF(a0, a1, b0)
    }
    {
      const bf16x8 a0 = AFRAG(2 * (NK2 - 1) + 1, 0);
      const bf16x8 a1 = AFRAG(2 * (NK2 - 1) + 1, 1);
      MFMA_HALF(a0, a1, b1)
    }
  }
#undef AFRAG
#undef MFMA_HALF

  // bias in fp32
#pragma unroll
  for (int nt = 0; nt < NT; ++nt) {
    float bvv = bias[n_base + nt * 16 + cl];
#pragma unroll
    for (int mt = 0; mt < 2; ++mt)
#pragma unroll
      for (int j = 0; j < 4; ++j) acc[mt][nt][j] += bvv;
  }

  __syncthreads();  // as dead
  float* redbuf = (float*)smem;  // [8][32]

  float rmax[2][4];
#pragma unroll
  for (int mt = 0; mt < 2; ++mt)
#pragma unroll
    for (int j = 0; j < 4; ++j) {
      float m = acc[mt][0][j];
#pragma unroll
      for (int nt = 1; nt < NT; ++nt) m = fmaxf(m, acc[mt][nt][j]);
      rmax[mt][j] = m;
    }
#pragma unroll
  for (int off = 1; off < 16; off <<= 1)
#pragma unroll
    for (int mt = 0; mt < 2; ++mt)
#pragma unroll
      for (int j = 0; j < 4; ++j)
        rmax[mt][j] = fmaxf(rmax[mt][j], __shfl_xor(rmax[mt][j], off));
  if (cl == 0) {
#pragma unroll
    for (int mt = 0; mt < 2; ++mt)
#pragma unroll
      for (int j = 0; j < 4; ++j) redbuf[w * 32 + mt * 16 + g * 4 + j] = rmax[mt][j];
  }
  __syncthreads();
  float rowmax[2][4];
#pragma unroll
  for (int mt = 0; mt < 2; ++mt)
#pragma unroll
    for (int j = 0; j < 4; ++j) {
      float m = redbuf[0 * 32 + mt * 16 + g * 4 + j];
#pragma unroll
      for (int ww = 1; ww < 8; ++ww) m = fmaxf(m, redbuf[ww * 32 + mt * 16 + g * 4 + j]);
      rowmax[mt][j] = m;
    }
  __syncthreads();

  float rsum[2][4];
#pragma unroll
  for (int mt = 0; mt < 2; ++mt)
#pragma unroll
    for (int j = 0; j < 4; ++j) {
      float s = 0.f;
#pragma unroll
      for (int nt = 0; nt < NT; ++nt) s += expf(acc[mt][nt][j] - rowmax[mt][j]);
      rsum[mt][j] = s;
    }
#pragma unroll
  for (int off = 1; off < 16; off <<= 1)
#pragma unroll
    for (int mt = 0; mt < 2; ++mt)
#pragma unroll
      for (int j = 0; j < 4; ++j) rsum[mt][j] += __shfl_xor(rsum[mt][j], off);
  if (cl == 0) {
#pragma unroll
    for (int mt = 0; mt < 2; ++mt)
#pragma unroll
      for (int j = 0; j < 4; ++j) redbuf[w * 32 + mt * 16 + g * 4 + j] = rsum[mt][j];
  }
  __syncthreads();
  float logz[2][4];
#pragma unroll
  for (int mt = 0; mt < 2; ++mt)
#pragma unroll
    for (int j = 0; j < 4; ++j) {
      float s = 0.f;
#pragma unroll
      for (int ww = 0; ww < 8; ++ww) s += redbuf[ww * 32 + mt * 16 + g * 4 + j];
      logz[mt][j] = rowmax[mt][j] + logf(s);
    }

  float* lpbuf = (float*)smem;  // [16][1024] = 64 KB
  for (int h = 0; h < 2; ++h) {
    __syncthreads();
#pragma unroll
    for (int nt = 0; nt < NT; ++nt)
#pragma unroll
      for (int j = 0; j < 4; ++j)
        lpbuf[(g * 4 + j) * 1024 + n_base + nt * 16 + cl] = acc[h][nt][j] - logz[h][j];
    __syncthreads();
    const int tot = 16 * S;
    for (int idx = tid; idx < tot; idx += 512) {
      int r = idx / S;
      int s = idx - r * S;
      long m = row0 + h * 16 + r;
      if (m < M) {
        int bb = (int)(m % B);
        int t = (int)(m / B);
        int lab = (s & 1) ? targets[bb * L + (s >> 1)] : 0;
        int grp = s / 5, rem = s - grp * 5;
        lp_ext[((long)bb * T + t) * LPROW + grp * 8 + rem] = lpbuf[r * 1024 + lab] * LOG2E;
      }
    }
  }
}

// ---------------------------------------------------------------------------
// CTC forward scan, base-2: one wave per batch element, alpha in registers
// (5 states/lane), neighbor exchange via shfl_up, CTC_DEPTH-deep register
// prefetch (aligned float4+float per lane via LPROW padding).
// ---------------------------------------------------------------------------
#define CTC_DEPTH 8
__global__ __launch_bounds__(64, 1) void ctc_scan_kernel(
    const float* __restrict__ lp2,  // (B, T, LPROW), log2 units
    const int* __restrict__ targets, const int* __restrict__ inlens,
    const int* __restrict__ tlens, float* __restrict__ partial,
    int T, int B, int L, int S)
{
  const int b = blockIdx.x;
  const int lane = threadIdx.x;
  const int s0 = lane * 5;
  const int inlen = inlens[b];
  const int tlen = tlens[b];
  const int send = 2 * tlen;
  const int capT = inlen - 1;

  bool valid[5], skipj[5];
#pragma unroll
  for (int j = 0; j < 5; ++j) {
    int s = s0 + j;
    valid[j] = (s < S);
    bool sk = false;
    if (valid[j] && (s & 1) && s >= 3) {
      int lab = targets[b * L + (s >> 1)];
      int lab2 = targets[b * L + (s >> 1) - 1];
      sk = (lab != 0) && (lab != lab2);
    }
    skipj[j] = sk;
  }

  const float* lpb = lp2 + (long)b * T * LPROW + lane * 8;

  float a[5];
  float lbv = NEGF, llv = NEGF;
#pragma unroll
  for (int j = 0; j < 5; ++j) {
    int s = s0 + j;
    a[j] = (valid[j] && s <= 1) ? lpb[j] : NEGF;
  }
  if (capT == 0) {
#pragma unroll
    for (int j = 0; j < 5; ++j) {
      int s = s0 + j;
      if (s == send) lbv = a[j];
      if (s == send - 1) llv = a[j];
    }
  }

  float4 b4[CTC_DEPTH];
  float b1[CTC_DEPTH];

#define CTC_ISSUE(d, t)                                \
  do {                                                 \
    const float* _p = lpb + (long)(t) * LPROW;         \
    b4[d] = *(const float4*)_p;                        \
    b1[d] = _p[4];                                     \
  } while (0)

#define CTC_PROCESS(tcur, d)                                                  \
  do {                                                                        \
    float lp_[5] = {b4[d].x, b4[d].y, b4[d].z, b4[d].w, b1[d]};               \
    float o_m1 = __shfl_up(a[4], 1);                                          \
    float o_m2 = __shfl_up(a[3], 1);                                          \
    if (lane == 0) { o_m1 = NEGF; o_m2 = NEGF; }                              \
    float na[5];                                                              \
    _Pragma("unroll")                                                         \
    for (int j = 0; j < 5; ++j) {                                             \
      float a0 = a[j];                                                        \
      float a1 = (j >= 1) ? a[j - 1] : o_m1;                                  \
      float a2 = skipj[j] ? ((j >= 2) ? a[j - 2] : o_m2) : NEGF;              \
      float m = fmaxf(fmaxf(a0, a1), a2);                                     \
      float sum = fast_exp2(a0 - m) + fast_exp2(a1 - m) + fast_exp2(a2 - m);  \
      float nv = m + fast_log2(sum) + lp_[j];                                 \
      na[j] = valid[j] ? nv : NEGF;                                           \
    }                                                                         \
    _Pragma("unroll")                                                         \
    for (int j = 0; j < 5; ++j) a[j] = na[j];                                 \
    if ((tcur) == capT) {                                                     \
      _Pragma("unroll")                                                       \
      for (int j = 0; j < 5; ++j) {                                           \
        int s = s0 + j;                                                       \
        if (s == send) lbv = a[j];                                            \
        if (s == send - 1) llv = a[j];                                        \
      }                                                                       \
    }                                                                         \
  } while (0)

#pragma unroll
  for (int d = 0; d < CTC_DEPTH; ++d) {
    int t = 1 + d;
    if (t < T) CTC_ISSUE(d, t);
  }

  int t = 1;
  for (; t <= T - 2 * CTC_DEPTH; t += CTC_DEPTH) {
#pragma unroll
    for (int d = 0; d < CTC_DEPTH; ++d) {
      CTC_PROCESS(t + d, d);
      CTC_ISSUE(d, t + d + CTC_DEPTH);
    }
  }
#pragma unroll
  for (int d = 0; d < CTC_DEPTH; ++d) {
    int tc = t + d;
    if (tc < T) {
      CTC_PROCESS(tc, d);
      int tn = tc + CTC_DEPTH;
      if (tn < T) CTC_ISSUE(d, tn);
    }
  }
  t += CTC_DEPTH;
#pragma unroll
  for (int d = 0; d < CTC_DEPTH; ++d) {
    int tc = t + d;
    if (tc < T) CTC_PROCESS(tc, d);
  }

#pragma unroll
  for (int off = 32; off; off >>= 1) {
    lbv = fmaxf(lbv, __shfl_xor(lbv, off));
    llv = fmaxf(llv, __shfl_xor(llv, off));
  }
  if (lane == 0) {
    float mx = fmaxf(lbv, llv);
    float l2 = mx + fast_log2(fast_exp2(lbv - mx) + fast_exp2(llv - mx));
    float loss = -LN2 * l2;
    if (!(loss <= 1e29f)) loss = 0.f;  // zero_infinity (also catches NaN)
    partial[b] = loss / (float)tlen;
  }
}

__global__ void reduce_kernel(const float* __restrict__ partial,
                              float* __restrict__ out, int B)
{
  int lane = threadIdx.x;
  float v = (lane < B) ? partial[lane] : 0.f;
#pragma unroll
  for (int off = 32; off; off >>= 1) v += __shfl_xor(v, off);
  if (lane == 0) out[0] = v / (float)B;
}

// ---------------------------------------------------------------------------
extern "C" void kernel_launch(void* const* d_in, const int* in_sizes, int n_in,
                              void* d_out, int out_size, void* d_ws, size_t ws_size,
                              hipStream_t stream) {
  const float* enc = (const float*)d_in[0];
  const float* Wp  = (const float*)d_in[1];
  const float* bp  = (const float*)d_in[2];
  const float* Wt  = (const float*)d_in[3];
  const float* btr = (const float*)d_in[4];
  const float* lng = (const float*)d_in[5];
  const float* lnb = (const float*)d_in[6];
  const float* Wd  = (const float*)d_in[7];
  const float* bd  = (const float*)d_in[8];
  const int* tgt   = (const int*)d_in[9];
  const int* inl   = (const int*)d_in[10];
  const int* tll   = (const int*)d_in[11];

  const int D = in_sizes[2];              // 768
  const int V = in_sizes[8];              // 1024
  const int B = in_sizes[10];             // 32
  const int L = in_sizes[9] / B;          // 150
  const long M = (long)in_sizes[0] / D;   // T*B = 64000
  const int T = (int)(M / B);             // 2000
  const int S = 2 * L + 1;                // 301

  char* wsb = (char*)d_ws;
  size_t off = 0;
  auto alloc = [&](size_t bytes) { char* p = wsb + off; off += (bytes + 255) & ~(size_t)255; return p; };
  unsigned short* X1b  = (unsigned short*)alloc((size_t)M * D * 2);
  unsigned short* X2b  = (unsigned short*)alloc((size_t)M * D * 2);
  float* LP            = (float*)alloc((size_t)B * T * LPROW * 4);
  unsigned short* WpT  = (unsigned short*)alloc((size_t)D * D * 2);
  unsigned short* WtT  = (unsigned short*)alloc((size_t)D * D * 2);
  unsigned short* WdT  = (unsigned short*)alloc((size_t)D * V * 2);
  float* partial       = (float*)alloc(256);

  cvt_wt_kernel<<<dim3(D / 32, D / 32), dim3(32, 8), 0, stream>>>(Wp, WpT, D, D);
  cvt_wt_kernel<<<dim3(D / 32, D / 32), dim3(32, 8), 0, stream>>>(Wt, WtT, D, D);
  cvt_wt_kernel<<<dim3(V / 32, D / 32), dim3(32, 8), 0, stream>>>(Wd, WdT, D, V);

  const int grid = (int)((M + 31) / 32);
  const size_t smem12 = 49152;  // max(A frag 48K, repack 48K)
  gemm_bf16_kernel<768, 6, 0, 1><<<grid, 512, smem12, stream>>>(
      (const void*)enc, WpT, bp, nullptr, nullptr, X1b, M);
  gemm_bf16_kernel<768, 6, 1, 0><<<grid, 512, smem12, stream>>>(
      (const void*)X1b, WtT, btr, lng, lnb, X2b, M);
  gemm3_bf16_kernel<768><<<grid, 512, 65536, stream>>>(
      X2b, WdT, bd, tgt, LP, M, T, B, L, S);

  ctc_scan_kernel<<<B, 64, 0, stream>>>(LP, tgt, inl, tll, partial, T, B, L, S);
  reduce_kernel<<<1, 64, 0, stream>>>(partial, (float*)d_out, B);
}

// Round 9
// 994.883 us; speedup vs baseline: 1.5800x; 1.5749x over previous
//
#include <hip/hip_runtime.h>
#include <hip/hip_bf16.h>
#include <math.h>
#include <stdint.h>

#define NEGF (-1e30f)
#define LOG2E 1.44269504088896340736f
#define LN2 0.69314718055994530942f

// lp row layout for the CTC scan: 64 lane-groups x 8 floats (5 used, 3 pad)
#define LPROW 512

typedef short bf16x8 __attribute__((ext_vector_type(8)));
typedef float f32x4 __attribute__((ext_vector_type(4)));

__device__ __forceinline__ unsigned short f2b(float x) {
  __hip_bfloat16 h = __float2bfloat16(x);
  return *reinterpret_cast<unsigned short*>(&h);
}
__device__ __forceinline__ float b2f(unsigned short u) {
  __hip_bfloat16 h;
  *reinterpret_cast<unsigned short*>(&h) = u;
  return __bfloat162float(h);
}
__device__ __forceinline__ float gelu_exact(float x) {
  return 0.5f * x * (1.0f + erff(x * 0.70710678118654752440f));
}

#if __has_builtin(__builtin_amdgcn_exp2f)
__device__ __forceinline__ float fast_exp2(float x) { return __builtin_amdgcn_exp2f(x); }
#else
__device__ __forceinline__ float fast_exp2(float x) { return exp2f(x); }
#endif
#if __has_builtin(__builtin_amdgcn_logf)
__device__ __forceinline__ float fast_log2(float x) { return __builtin_amdgcn_logf(x); }
#else
__device__ __forceinline__ float fast_log2(float x) { return log2f(x); }
#endif

// async global->LDS, 16B per lane. LDS dest = wave-uniform base + lane*16;
// global src is per-lane. Casts via integer round-trip (AS3 = low 32 bits of
// the generic shared address; AS1 = flat 64-bit address).
__device__ __forceinline__ void gload16(void* lds, const void* g) {
  __builtin_amdgcn_global_load_lds(
      (__attribute__((address_space(1))) void*)(uintptr_t)g,
      (__attribute__((address_space(3))) void*)(unsigned int)(uintptr_t)lds,
      16, 0, 0);
}

// ---------------------------------------------------------------------------
// fp32 -> bf16 elementwise
// ---------------------------------------------------------------------------
__global__ __launch_bounds__(256) void cvt_enc_kernel(
    const float* __restrict__ in, unsigned short* __restrict__ out, long n4)
{
  long i = (long)blockIdx.x * blockDim.x + threadIdx.x;
  const long stride = (long)gridDim.x * blockDim.x;
  for (; i < n4; i += stride) {
    float4 v = ((const float4*)in)[i];
    ushort4 o;
    o.x = f2b(v.x); o.y = f2b(v.y); o.z = f2b(v.z); o.w = f2b(v.w);
    ((ushort4*)out)[i] = o;
  }
}

// ---------------------------------------------------------------------------
// W (K,N) fp32 -> WT (N,K) bf16, 32x32 LDS tile transpose
// ---------------------------------------------------------------------------
__global__ __launch_bounds__(256) void cvt_wt_kernel(
    const float* __restrict__ W, unsigned short* __restrict__ WT, int K, int N)
{
  __shared__ float tile[32][33];
  const int n0 = blockIdx.x * 32, k0 = blockIdx.y * 32;
  const int tx = threadIdx.x, ty = threadIdx.y;  // 32 x 8
#pragma unroll
  for (int i = 0; i < 32; i += 8) {
    int k = k0 + ty + i, n = n0 + tx;
    tile[ty + i][tx] = (k < K && n < N) ? W[(long)k * N + n] : 0.f;
  }
  __syncthreads();
#pragma unroll
  for (int i = 0; i < 32; i += 8) {
    int n = n0 + ty + i, k = k0 + tx;
    if (n < N && k < K) WT[(long)n * K + k] = f2b(tile[tx][ty + i]);
  }
}

// ---------------------------------------------------------------------------
// m97-structure MFMA GEMM: 128x128 tile, BK=32, 256 threads (4 waves, 2x2).
// A (M,K) bf16 row-major; WT (N,K) bf16 row-major. Both tiles staged to LDS
// via global_load_lds (16B/lane), fragment-chunk order: chunk = r*4 + kc,
// 16B each -> lane (cl,g) frag read is 64 consecutive 16B chunks (no bank
// conflicts). 2-barrier K-loop: STAGE(next) || ds_read+MFMA(cur); barrier.
// EPI: 0 = bias -> bf16 out; 1 = bias+gelu -> bf16 out;
//      2 = bias -> bf16 scores out + per-(row, 64-col wave) online-softmax
//          partials (max, sumexp) at partials[m*16 + bx*2 + wc].
// M, N multiples of 128; K multiple of 32 (no guards needed: 64000,768/1024).
// ---------------------------------------------------------------------------
template<int NFULL, int EPI>
__global__ __launch_bounds__(256, 2) void gemm128_kernel(
    const unsigned short* __restrict__ A,
    const unsigned short* __restrict__ WT,
    const float* __restrict__ bias,
    unsigned short* __restrict__ out,
    float2* __restrict__ partials,
    int K)
{
  extern __shared__ char smem[];
  unsigned short* As = (unsigned short*)smem;            // 2 bufs x 4096 shorts
  unsigned short* Bs = (unsigned short*)(smem + 16384);  // 2 bufs x 4096 shorts

  const int tid = threadIdx.x, lane = tid & 63, w = tid >> 6;
  const int wr = w >> 1, wc = w & 1;
  const int cl = lane & 15, g = lane >> 4;
  const int bx = blockIdx.x;
  const long row0 = (long)blockIdx.y * 128;
  const int col0 = bx * 128;

  // staging: wave w covers chunks [w*64, w*64+64) and [256+w*64, ...)
  const int ch0 = w * 64 + lane;
  const int ch1 = 256 + ch0;
  const unsigned short* Ag0 = A + (row0 + (ch0 >> 2)) * K + (ch0 & 3) * 8;
  const unsigned short* Ag1 = A + (row0 + (ch1 >> 2)) * K + (ch1 & 3) * 8;
  const unsigned short* Bg0 = WT + (long)(col0 + (ch0 >> 2)) * K + (ch0 & 3) * 8;
  const unsigned short* Bg1 = WT + (long)(col0 + (ch1 >> 2)) * K + (ch1 & 3) * 8;
  unsigned short* Al0 = As + w * 512;           // wave-uniform LDS bases
  unsigned short* Al1 = As + 2048 + w * 512;
  unsigned short* Bl0 = Bs + w * 512;
  unsigned short* Bl1 = Bs + 2048 + w * 512;

#define STAGE(buf, kt)                          \
  do {                                          \
    const int _ko = (kt) * 32;                  \
    gload16(Al0 + (buf) * 4096, Ag0 + _ko);     \
    gload16(Al1 + (buf) * 4096, Ag1 + _ko);     \
    gload16(Bl0 + (buf) * 4096, Bg0 + _ko);     \
    gload16(Bl1 + (buf) * 4096, Bg1 + _ko);     \
  } while (0)

  f32x4 acc[4][4];
#pragma unroll
  for (int mt = 0; mt < 4; ++mt)
#pragma unroll
    for (int nt = 0; nt < 4; ++nt) acc[mt][nt] = (f32x4){0.f, 0.f, 0.f, 0.f};

  const int NKT = K / 32;
  STAGE(0, 0);
  __syncthreads();
  int buf = 0;
  for (int kt = 0; kt < NKT; ++kt) {
    if (kt + 1 < NKT) STAGE(buf ^ 1, kt + 1);
    const unsigned short* Ab = As + buf * 4096;
    const unsigned short* Bb = Bs + buf * 4096;
    bf16x8 af[4], bfr[4];
#pragma unroll
    for (int mt = 0; mt < 4; ++mt)
      af[mt] = *(const bf16x8*)&Ab[(((wr * 64 + mt * 16 + cl) << 2) + g) * 8];
#pragma unroll
    for (int nt = 0; nt < 4; ++nt)
      bfr[nt] = *(const bf16x8*)&Bb[(((wc * 64 + nt * 16 + cl) << 2) + g) * 8];
#pragma unroll
    for (int mt = 0; mt < 4; ++mt)
#pragma unroll
      for (int nt = 0; nt < 4; ++nt)
        acc[mt][nt] = __builtin_amdgcn_mfma_f32_16x16x32_bf16(
            af[mt], bfr[nt], acc[mt][nt], 0, 0, 0);
    __syncthreads();  // drains gload_lds (vmcnt) + protects buf swap
    buf ^= 1;
  }
#undef STAGE

  // ---- epilogue ----
  float bv[4];
#pragma unroll
  for (int nt = 0; nt < 4; ++nt) bv[nt] = bias[col0 + wc * 64 + nt * 16 + cl];
#pragma unroll
  for (int mt = 0; mt < 4; ++mt)
#pragma unroll
    for (int nt = 0; nt < 4; ++nt)
#pragma unroll
      for (int j = 0; j < 4; ++j) {
        float v = acc[mt][nt][j] + bv[nt];
        if (EPI == 1) v = gelu_exact(v);
        acc[mt][nt][j] = v;
      }

  if (EPI == 2) {
    // per-row partials over this wave's 64 cols (C/D: row=g*4+j, col=cl)
#pragma unroll
    for (int mt = 0; mt < 4; ++mt)
#pragma unroll
      for (int j = 0; j < 4; ++j) {
        float mx = fmaxf(fmaxf(acc[mt][0][j], acc[mt][1][j]),
                         fmaxf(acc[mt][2][j], acc[mt][3][j]));
#pragma unroll
        for (int off = 1; off < 16; off <<= 1)
          mx = fmaxf(mx, __shfl_xor(mx, off));
        float sm = 0.f;
#pragma unroll
        for (int nt = 0; nt < 4; ++nt) sm += expf(acc[mt][nt][j] - mx);
#pragma unroll
        for (int off = 1; off < 16; off <<= 1) sm += __shfl_xor(sm, off);
        if (cl == 0) {
          long m = row0 + wr * 64 + mt * 16 + g * 4 + j;
          partials[m * 16 + bx * 2 + wc] = make_float2(mx, sm);
        }
      }
  }

  // repack to bf16 via LDS (row stride 136 shorts: bank-stagger) and store
  unsigned short* Ct = (unsigned short*)smem;  // [128][136], 34816 B
#pragma unroll
  for (int mt = 0; mt < 4; ++mt)
#pragma unroll
    for (int nt = 0; nt < 4; ++nt)
#pragma unroll
      for (int j = 0; j < 4; ++j)
        Ct[(wr * 64 + mt * 16 + g * 4 + j) * 136 + wc * 64 + nt * 16 + cl] =
            f2b(acc[mt][nt][j]);
  __syncthreads();
  for (int idx = tid; idx < 2048; idx += 256) {
    int r = idx >> 4, ch = idx & 15;
    *(bf16x8*)&out[(row0 + r) * NFULL + col0 + ch * 8] =
        *(const bf16x8*)&Ct[r * 136 + ch * 8];
  }
}

// ---------------------------------------------------------------------------
// LayerNorm in place on bf16, one wave per row (known-good from round 2)
// ---------------------------------------------------------------------------
template<int D>
__global__ __launch_bounds__(256) void ln_bf16_kernel(
    unsigned short* __restrict__ X, const float* __restrict__ g,
    const float* __restrict__ bt, long M)
{
  constexpr int NI = D / 256;
  const int lane = threadIdx.x & 63;
  const int wid = threadIdx.x >> 6;
  const long row = (long)blockIdx.x * 4 + wid;
  if (row >= M) return;

  float v[NI * 4];
  float s = 0.f;
#pragma unroll
  for (int i = 0; i < NI; ++i) {
    ushort4 u = *(const ushort4*)&X[row * D + (i * 64 + lane) * 4];
    v[i * 4 + 0] = b2f(u.x); v[i * 4 + 1] = b2f(u.y);
    v[i * 4 + 2] = b2f(u.z); v[i * 4 + 3] = b2f(u.w);
    s += v[i * 4 + 0] + v[i * 4 + 1] + v[i * 4 + 2] + v[i * 4 + 3];
  }
#pragma unroll
  for (int off = 32; off; off >>= 1) s += __shfl_xor(s, off);
  const float mu = s * (1.0f / D);
  float q = 0.f;
#pragma unroll
  for (int i = 0; i < NI * 4; ++i) { float d = v[i] - mu; q += d * d; }
#pragma unroll
  for (int off = 32; off; off >>= 1) q += __shfl_xor(q, off);
  const float rs = rsqrtf(q * (1.0f / D) + 1e-6f);
#pragma unroll
  for (int i = 0; i < NI; ++i) {
    ushort4 o;
    int c = (i * 64 + lane) * 4;
    o.x = f2b((v[i * 4 + 0] - mu) * rs * g[c + 0] + bt[c + 0]);
    o.y = f2b((v[i * 4 + 1] - mu) * rs * g[c + 1] + bt[c + 1]);
    o.z = f2b((v[i * 4 + 2] - mu) * rs * g[c + 2] + bt[c + 2]);
    o.w = f2b((v[i * 4 + 3] - mu) * rs * g[c + 3] + bt[c + 3]);
    *(ushort4*)&X[row * D + c] = o;
  }
}

// ---------------------------------------------------------------------------
// logz combine (16 online-softmax partials per row) + label gather to the
// CTC (B,T,LPROW) layout in log2 units. One wave per row m = t*B + b.
// ---------------------------------------------------------------------------
__global__ __launch_bounds__(256) void logz_gather_kernel(
    const unsigned short* __restrict__ scores,  // (M, 1024) bf16
    const float2* __restrict__ partials,        // (M, 16)
    const int* __restrict__ targets,
    float* __restrict__ lp_ext,                 // (B, T, LPROW)
    long Mtot, int T, int B, int L, int S)
{
  const int w = threadIdx.x >> 6, lane = threadIdx.x & 63;
  const long m = (long)blockIdx.x * 4 + w;
  if (m >= Mtot) return;

  float2 pp = partials[m * 16 + (lane & 15)];
  float Mx = pp.x, Sv = pp.y;
#pragma unroll
  for (int off = 1; off < 16; off <<= 1) {
    float Mo = __shfl_xor(Mx, off);
    float So = __shfl_xor(Sv, off);
    float Mn = fmaxf(Mx, Mo);
    Sv = Sv * expf(Mx - Mn) + So * expf(Mo - Mn);
    Mx = Mn;
  }
  const float logz = Mx + logf(Sv);
  const int b = (int)(m % B);
  const int t = (int)(m / B);
  const unsigned short* srow = scores + m * 1024;
  float lp[5];
#pragma unroll
  for (int j = 0; j < 5; ++j) {
    int s = lane * 5 + j;
    int lab = ((s & 1) && s < S) ? targets[b * L + (s >> 1)] : 0;
    lp[j] = (b2f(srow[lab]) - logz) * LOG2E;
  }
  float* dst = lp_ext + ((long)b * T + t) * LPROW + lane * 8;
  *(float4*)dst = make_float4(lp[0], lp[1], lp[2], lp[3]);
  dst[4] = lp[4];
}

// ---------------------------------------------------------------------------
// CTC forward scan, base-2: one wave per batch element, alpha in registers
// (5 states/lane), neighbor exchange via shfl_up, CTC_DEPTH-deep register
// prefetch (aligned float4+float per lane via LPROW padding). (known-good)
// ---------------------------------------------------------------------------
#define CTC_DEPTH 8
__global__ __launch_bounds__(64, 1) void ctc_scan_kernel(
    const float* __restrict__ lp2,  // (B, T, LPROW), log2 units
    const int* __restrict__ targets, const int* __restrict__ inlens,
    const int* __restrict__ tlens, float* __restrict__ partial,
    int T, int B, int L, int S)
{
  const int b = blockIdx.x;
  const int lane = threadIdx.x;
  const int s0 = lane * 5;
  const int inlen = inlens[b];
  const int tlen = tlens[b];
  const int send = 2 * tlen;
  const int capT = inlen - 1;

  bool valid[5], skipj[5];
#pragma unroll
  for (int j = 0; j < 5; ++j) {
    int s = s0 + j;
    valid[j] = (s < S);
    bool sk = false;
    if (valid[j] && (s & 1) && s >= 3) {
      int lab = targets[b * L + (s >> 1)];
      int lab2 = targets[b * L + (s >> 1) - 1];
      sk = (lab != 0) && (lab != lab2);
    }
    skipj[j] = sk;
  }

  const float* lpb = lp2 + (long)b * T * LPROW + lane * 8;

  float a[5];
  float lbv = NEGF, llv = NEGF;
#pragma unroll
  for (int j = 0; j < 5; ++j) {
    int s = s0 + j;
    a[j] = (valid[j] && s <= 1) ? lpb[j] : NEGF;
  }
  if (capT == 0) {
#pragma unroll
    for (int j = 0; j < 5; ++j) {
      int s = s0 + j;
      if (s == send) lbv = a[j];
      if (s == send - 1) llv = a[j];
    }
  }

  float4 b4[CTC_DEPTH];
  float b1[CTC_DEPTH];

#define CTC_ISSUE(d, t)                                \
  do {                                                 \
    const float* _p = lpb + (long)(t) * LPROW;         \
    b4[d] = *(const float4*)_p;                        \
    b1[d] = _p[4];                                     \
  } while (0)

#define CTC_PROCESS(tcur, d)                                                  \
  do {                                                                        \
    float lp_[5] = {b4[d].x, b4[d].y, b4[d].z, b4[d].w, b1[d]};               \
    float o_m1 = __shfl_up(a[4], 1);                                          \
    float o_m2 = __shfl_up(a[3], 1);                                          \
    if (lane == 0) { o_m1 = NEGF; o_m2 = NEGF; }                              \
    float na[5];                                                              \
    _Pragma("unroll")                                                         \
    for (int j = 0; j < 5; ++j) {                                             \
      float a0 = a[j];                                                        \
      float a1 = (j >= 1) ? a[j - 1] : o_m1;                                  \
      float a2 = skipj[j] ? ((j >= 2) ? a[j - 2] : o_m2) : NEGF;              \
      float m = fmaxf(fmaxf(a0, a1), a2);                                     \
      float sum = fast_exp2(a0 - m) + fast_exp2(a1 - m) + fast_exp2(a2 - m);  \
      float nv = m + fast_log2(sum) + lp_[j];                                 \
      na[j] = valid[j] ? nv : NEGF;                                           \
    }                                                                         \
    _Pragma("unroll")                                                         \
    for (int j = 0; j < 5; ++j) a[j] = na[j];                                 \
    if ((tcur) == capT) {                                                     \
      _Pragma("unroll")                                                       \
      for (int j = 0; j < 5; ++j) {                                           \
        int s = s0 + j;                                                       \
        if (s == send) lbv = a[j];                                            \
        if (s == send - 1) llv = a[j];                                        \
      }                                                                       \
    }                                                                         \
  } while (0)

#pragma unroll
  for (int d = 0; d < CTC_DEPTH; ++d) {
    int t = 1 + d;
    if (t < T) CTC_ISSUE(d, t);
  }

  int t = 1;
  for (; t <= T - 2 * CTC_DEPTH; t += CTC_DEPTH) {
#pragma unroll
    for (int d = 0; d < CTC_DEPTH; ++d) {
      CTC_PROCESS(t + d, d);
      CTC_ISSUE(d, t + d + CTC_DEPTH);
    }
  }
#pragma unroll
  for (int d = 0; d < CTC_DEPTH; ++d) {
    int tc = t + d;
    if (tc < T) {
      CTC_PROCESS(tc, d);
      int tn = tc + CTC_DEPTH;
      if (tn < T) CTC_ISSUE(d, tn);
    }
  }
  t += CTC_DEPTH;
#pragma unroll
  for (int d = 0; d < CTC_DEPTH; ++d) {
    int tc = t + d;
    if (tc < T) CTC_PROCESS(tc, d);
  }

#pragma unroll
  for (int off = 32; off; off >>= 1) {
    lbv = fmaxf(lbv, __shfl_xor(lbv, off));
    llv = fmaxf(llv, __shfl_xor(llv, off));
  }
  if (lane == 0) {
    float mx = fmaxf(lbv, llv);
    float l2 = mx + fast_log2(fast_exp2(lbv - mx) + fast_exp2(llv - mx));
    float loss = -LN2 * l2;
    if (!(loss <= 1e29f)) loss = 0.f;  // zero_infinity (also catches NaN)
    partial[b] = loss / (float)tlen;
  }
}

__global__ void reduce_kernel(const float* __restrict__ partial,
                              float* __restrict__ out, int B)
{
  int lane = threadIdx.x;
  float v = (lane < B) ? partial[lane] : 0.f;
#pragma unroll
  for (int off = 32; off; off >>= 1) v += __shfl_xor(v, off);
  if (lane == 0) out[0] = v / (float)B;
}

// ---------------------------------------------------------------------------
extern "C" void kernel_launch(void* const* d_in, const int* in_sizes, int n_in,
                              void* d_out, int out_size, void* d_ws, size_t ws_size,
                              hipStream_t stream) {
  const float* enc = (const float*)d_in[0];
  const float* Wp  = (const float*)d_in[1];
  const float* bp  = (const float*)d_in[2];
  const float* Wt  = (const float*)d_in[3];
  const float* btr = (const float*)d_in[4];
  const float* lng = (const float*)d_in[5];
  const float* lnb = (const float*)d_in[6];
  const float* Wd  = (const float*)d_in[7];
  const float* bd  = (const float*)d_in[8];
  const int* tgt   = (const int*)d_in[9];
  const int* inl   = (const int*)d_in[10];
  const int* tll   = (const int*)d_in[11];

  const int D = in_sizes[2];              // 768
  const int V = in_sizes[8];              // 1024
  const int B = in_sizes[10];             // 32
  const int L = in_sizes[9] / B;          // 150
  const long M = (long)in_sizes[0] / D;   // T*B = 64000
  const int T = (int)(M / B);             // 2000
  const int S = 2 * L + 1;                // 301

  char* wsb = (char*)d_ws;
  size_t off = 0;
  auto alloc = [&](size_t bytes) { char* p = wsb + off; off += (bytes + 255) & ~(size_t)255; return p; };
  unsigned short* encb   = (unsigned short*)alloc((size_t)M * D * 2);   // X2b aliases
  char* x1region         = alloc((size_t)M * V * 2);                    // 131 MB
  unsigned short* X1b    = (unsigned short*)x1region;   // dead after gemm2
  unsigned short* scores = (unsigned short*)x1region;   // written by gemm3
  unsigned short* X2b    = encb;                        // encb dead after gemm1
  float* LP              = (float*)alloc((size_t)B * T * LPROW * 4);
  float2* partials       = (float2*)alloc((size_t)M * 16 * sizeof(float2));
  unsigned short* WpT    = (unsigned short*)alloc((size_t)D * D * 2);
  unsigned short* WtT    = (unsigned short*)alloc((size_t)D * D * 2);
  unsigned short* WdT    = (unsigned short*)alloc((size_t)D * V * 2);
  float* partial         = (float*)alloc(256);

  cvt_wt_kernel<<<dim3(D / 32, D / 32), dim3(32, 8), 0, stream>>>(Wp, WpT, D, D);
  cvt_wt_kernel<<<dim3(D / 32, D / 32), dim3(32, 8), 0, stream>>>(Wt, WtT, D, D);
  cvt_wt_kernel<<<dim3(V / 32, D / 32), dim3(32, 8), 0, stream>>>(Wd, WdT, D, V);
  cvt_enc_kernel<<<2048, 256, 0, stream>>>(enc, encb, (long)M * D / 4);

  const size_t smemg = 34816;  // max(2x(8K A + 8K B), 128x136 bf16 repack)
  const dim3 g12(D / 128, (unsigned)(M / 128));   // (6, 500)
  const dim3 g3(V / 128, (unsigned)(M / 128));    // (8, 500)

  gemm128_kernel<768, 0><<<g12, 256, smemg, stream>>>(encb, WpT, bp, X1b, nullptr, D);
  gemm128_kernel<768, 1><<<g12, 256, smemg, stream>>>(X1b, WtT, btr, X2b, nullptr, D);
  ln_bf16_kernel<768><<<(int)(M / 4), 256, 0, stream>>>(X2b, lng, lnb, M);
  gemm128_kernel<1024, 2><<<g3, 256, smemg, stream>>>(X2b, WdT, bd, scores, partials, D);

  logz_gather_kernel<<<(int)(M / 4), 256, 0, stream>>>(
      scores, partials, tgt, LP, M, T, B, L, S);
  ctc_scan_kernel<<<B, 64, 0, stream>>>(LP, tgt, inl, tll, partial, T, B, L, S);
  reduce_kernel<<<1, 64, 0, stream>>>(partial, (float*)d_out, B);
}

// Round 10
// 809.119 us; speedup vs baseline: 1.9428x; 1.2296x over previous
//
#include <hip/hip_runtime.h>
#include <hip/hip_bf16.h>
#include <math.h>
#include <stdint.h>

#define NEGF (-1e30f)
#define LOG2E 1.44269504088896340736f
#define LN2 0.69314718055994530942f

// lp row layout for the CTC scan: 64 lane-groups x 8 floats (5 used, 3 pad)
#define LPROW 512

typedef short bf16x8 __attribute__((ext_vector_type(8)));
typedef float f32x4 __attribute__((ext_vector_type(4)));

__device__ __forceinline__ unsigned short f2b(float x) {
  __hip_bfloat16 h = __float2bfloat16(x);
  return *reinterpret_cast<unsigned short*>(&h);
}
__device__ __forceinline__ float b2f(unsigned short u) {
  __hip_bfloat16 h;
  *reinterpret_cast<unsigned short*>(&h) = u;
  return __bfloat162float(h);
}
__device__ __forceinline__ float gelu_exact(float x) {
  return 0.5f * x * (1.0f + erff(x * 0.70710678118654752440f));
}

#if __has_builtin(__builtin_amdgcn_logf)
__device__ __forceinline__ float fast_log2(float x) { return __builtin_amdgcn_logf(x); }
#else
__device__ __forceinline__ float fast_log2(float x) { return log2f(x); }
#endif

// async global->LDS, 16B per lane. LDS dest = wave-uniform base + lane*16;
// global src is per-lane.
__device__ __forceinline__ void gload16(void* lds, const void* g) {
  __builtin_amdgcn_global_load_lds(
      (__attribute__((address_space(1))) void*)(uintptr_t)g,
      (__attribute__((address_space(3))) void*)(unsigned int)(uintptr_t)lds,
      16, 0, 0);
}

// ---------------------------------------------------------------------------
// fp32 -> bf16 elementwise
// ---------------------------------------------------------------------------
__global__ __launch_bounds__(256) void cvt_enc_kernel(
    const float* __restrict__ in, unsigned short* __restrict__ out, long n4)
{
  long i = (long)blockIdx.x * blockDim.x + threadIdx.x;
  const long stride = (long)gridDim.x * blockDim.x;
  for (; i < n4; i += stride) {
    float4 v = ((const float4*)in)[i];
    ushort4 o;
    o.x = f2b(v.x); o.y = f2b(v.y); o.z = f2b(v.z); o.w = f2b(v.w);
    ((ushort4*)out)[i] = o;
  }
}

// ---------------------------------------------------------------------------
// W (K,N) fp32 -> WT (N,K) bf16, 32x32 LDS tile transpose
// ---------------------------------------------------------------------------
__global__ __launch_bounds__(256) void cvt_wt_kernel(
    const float* __restrict__ W, unsigned short* __restrict__ WT, int K, int N)
{
  __shared__ float tile[32][33];
  const int n0 = blockIdx.x * 32, k0 = blockIdx.y * 32;
  const int tx = threadIdx.x, ty = threadIdx.y;  // 32 x 8
#pragma unroll
  for (int i = 0; i < 32; i += 8) {
    int k = k0 + ty + i, n = n0 + tx;
    tile[ty + i][tx] = (k < K && n < N) ? W[(long)k * N + n] : 0.f;
  }
  __syncthreads();
#pragma unroll
  for (int i = 0; i < 32; i += 8) {
    int n = n0 + ty + i, k = k0 + tx;
    if (n < N && k < K) WT[(long)n * K + k] = f2b(tile[tx][ty + i]);
  }
}

// ---------------------------------------------------------------------------
// m97-structure MFMA GEMM: 128x128 tile, BK=32, 256 threads (4 waves, 2x2).
// (unchanged from round 9 — passing, 3x faster than the streamed structure)
// ---------------------------------------------------------------------------
template<int NFULL, int EPI>
__global__ __launch_bounds__(256, 2) void gemm128_kernel(
    const unsigned short* __restrict__ A,
    const unsigned short* __restrict__ WT,
    const float* __restrict__ bias,
    unsigned short* __restrict__ out,
    float2* __restrict__ partials,
    int K)
{
  extern __shared__ char smem[];
  unsigned short* As = (unsigned short*)smem;            // 2 bufs x 4096 shorts
  unsigned short* Bs = (unsigned short*)(smem + 16384);  // 2 bufs x 4096 shorts

  const int tid = threadIdx.x, lane = tid & 63, w = tid >> 6;
  const int wr = w >> 1, wc = w & 1;
  const int cl = lane & 15, g = lane >> 4;
  const int bx = blockIdx.x;
  const long row0 = (long)blockIdx.y * 128;
  const int col0 = bx * 128;

  const int ch0 = w * 64 + lane;
  const int ch1 = 256 + ch0;
  const unsigned short* Ag0 = A + (row0 + (ch0 >> 2)) * K + (ch0 & 3) * 8;
  const unsigned short* Ag1 = A + (row0 + (ch1 >> 2)) * K + (ch1 & 3) * 8;
  const unsigned short* Bg0 = WT + (long)(col0 + (ch0 >> 2)) * K + (ch0 & 3) * 8;
  const unsigned short* Bg1 = WT + (long)(col0 + (ch1 >> 2)) * K + (ch1 & 3) * 8;
  unsigned short* Al0 = As + w * 512;
  unsigned short* Al1 = As + 2048 + w * 512;
  unsigned short* Bl0 = Bs + w * 512;
  unsigned short* Bl1 = Bs + 2048 + w * 512;

#define STAGE(buf, kt)                          \
  do {                                          \
    const int _ko = (kt) * 32;                  \
    gload16(Al0 + (buf) * 4096, Ag0 + _ko);     \
    gload16(Al1 + (buf) * 4096, Ag1 + _ko);     \
    gload16(Bl0 + (buf) * 4096, Bg0 + _ko);     \
    gload16(Bl1 + (buf) * 4096, Bg1 + _ko);     \
  } while (0)

  f32x4 acc[4][4];
#pragma unroll
  for (int mt = 0; mt < 4; ++mt)
#pragma unroll
    for (int nt = 0; nt < 4; ++nt) acc[mt][nt] = (f32x4){0.f, 0.f, 0.f, 0.f};

  const int NKT = K / 32;
  STAGE(0, 0);
  __syncthreads();
  int buf = 0;
  for (int kt = 0; kt < NKT; ++kt) {
    if (kt + 1 < NKT) STAGE(buf ^ 1, kt + 1);
    const unsigned short* Ab = As + buf * 4096;
    const unsigned short* Bb = Bs + buf * 4096;
    bf16x8 af[4], bfr[4];
#pragma unroll
    for (int mt = 0; mt < 4; ++mt)
      af[mt] = *(const bf16x8*)&Ab[(((wr * 64 + mt * 16 + cl) << 2) + g) * 8];
#pragma unroll
    for (int nt = 0; nt < 4; ++nt)
      bfr[nt] = *(const bf16x8*)&Bb[(((wc * 64 + nt * 16 + cl) << 2) + g) * 8];
#pragma unroll
    for (int mt = 0; mt < 4; ++mt)
#pragma unroll
      for (int nt = 0; nt < 4; ++nt)
        acc[mt][nt] = __builtin_amdgcn_mfma_f32_16x16x32_bf16(
            af[mt], bfr[nt], acc[mt][nt], 0, 0, 0);
    __syncthreads();
    buf ^= 1;
  }
#undef STAGE

  float bv[4];
#pragma unroll
  for (int nt = 0; nt < 4; ++nt) bv[nt] = bias[col0 + wc * 64 + nt * 16 + cl];
#pragma unroll
  for (int mt = 0; mt < 4; ++mt)
#pragma unroll
    for (int nt = 0; nt < 4; ++nt)
#pragma unroll
      for (int j = 0; j < 4; ++j) {
        float v = acc[mt][nt][j] + bv[nt];
        if (EPI == 1) v = gelu_exact(v);
        acc[mt][nt][j] = v;
      }

  if (EPI == 2) {
#pragma unroll
    for (int mt = 0; mt < 4; ++mt)
#pragma unroll
      for (int j = 0; j < 4; ++j) {
        float mx = fmaxf(fmaxf(acc[mt][0][j], acc[mt][1][j]),
                         fmaxf(acc[mt][2][j], acc[mt][3][j]));
#pragma unroll
        for (int off = 1; off < 16; off <<= 1)
          mx = fmaxf(mx, __shfl_xor(mx, off));
        float sm = 0.f;
#pragma unroll
        for (int nt = 0; nt < 4; ++nt) sm += expf(acc[mt][nt][j] - mx);
#pragma unroll
        for (int off = 1; off < 16; off <<= 1) sm += __shfl_xor(sm, off);
        if (cl == 0) {
          long m = row0 + wr * 64 + mt * 16 + g * 4 + j;
          partials[m * 16 + bx * 2 + wc] = make_float2(mx, sm);
        }
      }
  }

  unsigned short* Ct = (unsigned short*)smem;  // [128][136]
#pragma unroll
  for (int mt = 0; mt < 4; ++mt)
#pragma unroll
    for (int nt = 0; nt < 4; ++nt)
#pragma unroll
      for (int j = 0; j < 4; ++j)
        Ct[(wr * 64 + mt * 16 + g * 4 + j) * 136 + wc * 64 + nt * 16 + cl] =
            f2b(acc[mt][nt][j]);
  __syncthreads();
  for (int idx = tid; idx < 2048; idx += 256) {
    int r = idx >> 4, ch = idx & 15;
    *(bf16x8*)&out[(row0 + r) * NFULL + col0 + ch * 8] =
        *(const bf16x8*)&Ct[r * 136 + ch * 8];
  }
}

// ---------------------------------------------------------------------------
// LayerNorm in place on bf16, one wave per row
// ---------------------------------------------------------------------------
template<int D>
__global__ __launch_bounds__(256) void ln_bf16_kernel(
    unsigned short* __restrict__ X, const float* __restrict__ g,
    const float* __restrict__ bt, long M)
{
  constexpr int NI = D / 256;
  const int lane = threadIdx.x & 63;
  const int wid = threadIdx.x >> 6;
  const long row = (long)blockIdx.x * 4 + wid;
  if (row >= M) return;

  float v[NI * 4];
  float s = 0.f;
#pragma unroll
  for (int i = 0; i < NI; ++i) {
    ushort4 u = *(const ushort4*)&X[row * D + (i * 64 + lane) * 4];
    v[i * 4 + 0] = b2f(u.x); v[i * 4 + 1] = b2f(u.y);
    v[i * 4 + 2] = b2f(u.z); v[i * 4 + 3] = b2f(u.w);
    s += v[i * 4 + 0] + v[i * 4 + 1] + v[i * 4 + 2] + v[i * 4 + 3];
  }
#pragma unroll
  for (int off = 32; off; off >>= 1) s += __shfl_xor(s, off);
  const float mu = s * (1.0f / D);
  float q = 0.f;
#pragma unroll
  for (int i = 0; i < NI * 4; ++i) { float d = v[i] - mu; q += d * d; }
#pragma unroll
  for (int off = 32; off; off >>= 1) q += __shfl_xor(q, off);
  const float rs = rsqrtf(q * (1.0f / D) + 1e-6f);
#pragma unroll
  for (int i = 0; i < NI; ++i) {
    ushort4 o;
    int c = (i * 64 + lane) * 4;
    o.x = f2b((v[i * 4 + 0] - mu) * rs * g[c + 0] + bt[c + 0]);
    o.y = f2b((v[i * 4 + 1] - mu) * rs * g[c + 1] + bt[c + 1]);
    o.z = f2b((v[i * 4 + 2] - mu) * rs * g[c + 2] + bt[c + 2]);
    o.w = f2b((v[i * 4 + 3] - mu) * rs * g[c + 3] + bt[c + 3]);
    *(ushort4*)&X[row * D + c] = o;
  }
}

// ---------------------------------------------------------------------------
// logz combine + label gather. NOW stores LINEAR probabilities scaled by
// 2^10: p'[s] = exp(score[lab] - logz) * 1024. One wave per row m = t*B + b.
// ---------------------------------------------------------------------------
__global__ __launch_bounds__(256) void logz_gather_kernel(
    const unsigned short* __restrict__ scores,  // (M, 1024) bf16
    const float2* __restrict__ partials,        // (M, 16)
    const int* __restrict__ targets,
    float* __restrict__ lp_ext,                 // (B, T, LPROW)
    long Mtot, int T, int B, int L, int S)
{
  const int w = threadIdx.x >> 6, lane = threadIdx.x & 63;
  const long m = (long)blockIdx.x * 4 + w;
  if (m >= Mtot) return;

  float2 pp = partials[m * 16 + (lane & 15)];
  float Mx = pp.x, Sv = pp.y;
#pragma unroll
  for (int off = 1; off < 16; off <<= 1) {
    float Mo = __shfl_xor(Mx, off);
    float So = __shfl_xor(Sv, off);
    float Mn = fmaxf(Mx, Mo);
    Sv = Sv * expf(Mx - Mn) + So * expf(Mo - Mn);
    Mx = Mn;
  }
  const float logz = Mx + logf(Sv);
  const int b = (int)(m % B);
  const int t = (int)(m / B);
  const unsigned short* srow = scores + m * 1024;
  float lp[5];
#pragma unroll
  for (int j = 0; j < 5; ++j) {
    int s = lane * 5 + j;
    int lab = ((s & 1) && s < S) ? targets[b * L + (s >> 1)] : 0;
    lp[j] = expf(b2f(srow[lab]) - logz) * 1024.0f;  // p * 2^10
  }
  float* dst = lp_ext + ((long)b * T + t) * LPROW + lane * 8;
  *(float4*)dst = make_float4(lp[0], lp[1], lp[2], lp[3]);
  dst[4] = lp[4];
}

// ---------------------------------------------------------------------------
// CTC forward scan, LINEAR DOMAIN: one wave per batch element, alpha' in
// registers (5 states/lane), neighbor exchange via shfl_up, 8-deep register
// prefetch. alpha' tracks true alpha x 2^(10*rows - corr); renorm every
// chunk by an exact power of 2 (frexp/ldexp) with corr accumulation.
// NO transcendentals in the 2000-step loop.
// ---------------------------------------------------------------------------
#define CTC_DEPTH 8
__global__ __launch_bounds__(64, 1) void ctc_scan_kernel(
    const float* __restrict__ pr,  // (B, T, LPROW): softmax prob * 1024
    const int* __restrict__ targets, const int* __restrict__ inlens,
    const int* __restrict__ tlens, float* __restrict__ partial,
    int T, int B, int L, int S)
{
  const int b = blockIdx.x;
  const int lane = threadIdx.x;
  const int s0 = lane * 5;
  const int inlen = inlens[b];
  const int tlen = tlens[b];
  const int send = 2 * tlen;
  const int capT = inlen - 1;

  bool valid[5];
  float skm[5];  // skip multiplier 0/1
#pragma unroll
  for (int j = 0; j < 5; ++j) {
    int s = s0 + j;
    valid[j] = (s < S);
    float sk = 0.f;
    if (valid[j] && (s & 1) && s >= 3) {
      int lab = targets[b * L + (s >> 1)];
      int lab2 = targets[b * L + (s >> 1) - 1];
      sk = ((lab != 0) && (lab != lab2)) ? 1.f : 0.f;
    }
    skm[j] = sk;
  }

  const float* pb = pr + (long)b * T * LPROW + lane * 8;

  float a[5];
  float abv = 0.f, alv = 0.f;  // alpha'[send], alpha'[send-1] at capT
  int corr = 0, corr_cap = 0;
#pragma unroll
  for (int j = 0; j < 5; ++j) {
    int s = s0 + j;
    a[j] = (valid[j] && s <= 1) ? pb[j] : 0.f;
  }
  if (capT == 0) {
#pragma unroll
    for (int j = 0; j < 5; ++j) {
      int s = s0 + j;
      if (s == send) abv = a[j];
      if (s == send - 1) alv = a[j];
    }
    corr_cap = corr;
  }

  float4 b4[CTC_DEPTH];
  float b1[CTC_DEPTH];

#define CTC_ISSUE(d, t)                                \
  do {                                                 \
    const float* _p = pb + (long)(t) * LPROW;          \
    b4[d] = *(const float4*)_p;                        \
    b1[d] = _p[4];                                     \
  } while (0)

#define CTC_PROCESS(tcur, d)                                                  \
  do {                                                                        \
    float p_[5] = {b4[d].x, b4[d].y, b4[d].z, b4[d].w, b1[d]};                \
    float o_m1 = __shfl_up(a[4], 1);                                          \
    float o_m2 = __shfl_up(a[3], 1);                                          \
    if (lane == 0) { o_m1 = 0.f; o_m2 = 0.f; }                                \
    float na[5];                                                              \
    _Pragma("unroll")                                                         \
    for (int j = 0; j < 5; ++j) {                                             \
      float a1 = (j >= 1) ? a[j - 1] : o_m1;                                  \
      float a2 = (j >= 2) ? a[j - 2] : o_m2;                                  \
      float sum = fmaf(skm[j], a2, a[j] + a1);                                \
      na[j] = valid[j] ? sum * p_[j] : 0.f;                                   \
    }                                                                         \
    _Pragma("unroll")                                                         \
    for (int j = 0; j < 5; ++j) a[j] = na[j];                                 \
    if ((tcur) == capT) {                                                     \
      _Pragma("unroll")                                                       \
      for (int j = 0; j < 5; ++j) {                                           \
        int s = s0 + j;                                                       \
        if (s == send) abv = a[j];                                            \
        if (s == send - 1) alv = a[j];                                        \
      }                                                                       \
      corr_cap = corr;                                                        \
    }                                                                         \
  } while (0)

  // exact power-of-2 wave renorm: keeps alpha' max in [0.5, 1)
#define CTC_RENORM                                                            \
  do {                                                                        \
    float mx = fmaxf(fmaxf(fmaxf(a[0], a[1]), fmaxf(a[2], a[3])), a[4]);      \
    _Pragma("unroll")                                                         \
    for (int off = 1; off < 64; off <<= 1)                                    \
      mx = fmaxf(mx, __shfl_xor(mx, off));                                    \
    int e;                                                                    \
    (void)frexpf(mx, &e);  /* mx == 0 -> e = 0 -> no-op */                    \
    float sc = ldexpf(1.f, -e);                                               \
    _Pragma("unroll")                                                         \
    for (int j = 0; j < 5; ++j) a[j] *= sc;                                   \
    corr += e;                                                                \
  } while (0)

#pragma unroll
  for (int d = 0; d < CTC_DEPTH; ++d) {
    int t = 1 + d;
    if (t < T) CTC_ISSUE(d, t);
  }

  int t = 1;
  for (; t <= T - 2 * CTC_DEPTH; t += CTC_DEPTH) {
#pragma unroll
    for (int d = 0; d < CTC_DEPTH; ++d) {
      CTC_PROCESS(t + d, d);
      CTC_ISSUE(d, t + d + CTC_DEPTH);
    }
    CTC_RENORM;
  }
#pragma unroll
  for (int d = 0; d < CTC_DEPTH; ++d) {
    int tc = t + d;
    if (tc < T) {
      CTC_PROCESS(tc, d);
      int tn = tc + CTC_DEPTH;
      if (tn < T) CTC_ISSUE(d, tn);
    }
  }
  CTC_RENORM;
  t += CTC_DEPTH;
#pragma unroll
  for (int d = 0; d < CTC_DEPTH; ++d) {
    int tc = t + d;
    if (tc < T) CTC_PROCESS(tc, d);
  }

  // reduce the (single-lane-held) captures across the wave
#pragma unroll
  for (int off = 32; off; off >>= 1) {
    abv = fmaxf(abv, __shfl_xor(abv, off));
    alv = fmaxf(alv, __shfl_xor(alv, off));
  }
  if (lane == 0) {
    // true log2(alpha) = log2(alpha') + corr_cap - 10*inlen
    float l2 = fast_log2(abv + alv) + (float)corr_cap - 10.0f * (float)inlen;
    float loss = -LN2 * l2;
    if (!(loss <= 1e29f)) loss = 0.f;  // zero_infinity (also catches NaN/inf)
    partial[b] = loss / (float)tlen;
  }
}

__global__ void reduce_kernel(const float* __restrict__ partial,
                              float* __restrict__ out, int B)
{
  int lane = threadIdx.x;
  float v = (lane < B) ? partial[lane] : 0.f;
#pragma unroll
  for (int off = 32; off; off >>= 1) v += __shfl_xor(v, off);
  if (lane == 0) out[0] = v / (float)B;
}

// ---------------------------------------------------------------------------
extern "C" void kernel_launch(void* const* d_in, const int* in_sizes, int n_in,
                              void* d_out, int out_size, void* d_ws, size_t ws_size,
                              hipStream_t stream) {
  const float* enc = (const float*)d_in[0];
  const float* Wp  = (const float*)d_in[1];
  const float* bp  = (const float*)d_in[2];
  const float* Wt  = (const float*)d_in[3];
  const float* btr = (const float*)d_in[4];
  const float* lng = (const float*)d_in[5];
  const float* lnb = (const float*)d_in[6];
  const float* Wd  = (const float*)d_in[7];
  const float* bd  = (const float*)d_in[8];
  const int* tgt   = (const int*)d_in[9];
  const int* inl   = (const int*)d_in[10];
  const int* tll   = (const int*)d_in[11];

  const int D = in_sizes[2];              // 768
  const int V = in_sizes[8];              // 1024
  const int B = in_sizes[10];             // 32
  const int L = in_sizes[9] / B;          // 150
  const long M = (long)in_sizes[0] / D;   // T*B = 64000
  const int T = (int)(M / B);             // 2000
  const int S = 2 * L + 1;                // 301

  char* wsb = (char*)d_ws;
  size_t off = 0;
  auto alloc = [&](size_t bytes) { char* p = wsb + off; off += (bytes + 255) & ~(size_t)255; return p; };
  unsigned short* encb   = (unsigned short*)alloc((size_t)M * D * 2);
  char* x1region         = alloc((size_t)M * V * 2);
  unsigned short* X1b    = (unsigned short*)x1region;   // dead after gemm2
  unsigned short* scores = (unsigned short*)x1region;   // written by gemm3
  unsigned short* X2b    = encb;                        // encb dead after gemm1
  float* LP              = (float*)alloc((size_t)B * T * LPROW * 4);
  float2* partials       = (float2*)alloc((size_t)M * 16 * sizeof(float2));
  unsigned short* WpT    = (unsigned short*)alloc((size_t)D * D * 2);
  unsigned short* WtT    = (unsigned short*)alloc((size_t)D * D * 2);
  unsigned short* WdT    = (unsigned short*)alloc((size_t)D * V * 2);
  float* partial         = (float*)alloc(256);

  cvt_wt_kernel<<<dim3(D / 32, D / 32), dim3(32, 8), 0, stream>>>(Wp, WpT, D, D);
  cvt_wt_kernel<<<dim3(D / 32, D / 32), dim3(32, 8), 0, stream>>>(Wt, WtT, D, D);
  cvt_wt_kernel<<<dim3(V / 32, D / 32), dim3(32, 8), 0, stream>>>(Wd, WdT, D, V);
  cvt_enc_kernel<<<2048, 256, 0, stream>>>(enc, encb, (long)M * D / 4);

  const size_t smemg = 34816;
  const dim3 g12(D / 128, (unsigned)(M / 128));   // (6, 500)
  const dim3 g3(V / 128, (unsigned)(M / 128));    // (8, 500)

  gemm128_kernel<768, 0><<<g12, 256, smemg, stream>>>(encb, WpT, bp, X1b, nullptr, D);
  gemm128_kernel<768, 1><<<g12, 256, smemg, stream>>>(X1b, WtT, btr, X2b, nullptr, D);
  ln_bf16_kernel<768><<<(int)(M / 4), 256, 0, stream>>>(X2b, lng, lnb, M);
  gemm128_kernel<1024, 2><<<g3, 256, smemg, stream>>>(X2b, WdT, bd, scores, partials, D);

  logz_gather_kernel<<<(int)(M / 4), 256, 0, stream>>>(
      scores, partials, tgt, LP, M, T, B, L, S);
  ctc_scan_kernel<<<B, 64, 0, stream>>>(LP, tgt, inl, tll, partial, T, B, L, S);
  reduce_kernel<<<1, 64, 0, stream>>>(partial, (float*)d_out, B);
}